// Round 3
// baseline (855.761 us; speedup 1.0000x reference)
//
#include <hip/hip_runtime.h>

// GAT (3-layer) on MI355X.
// R2: (a) CSR-build kernels process 4 edges/thread (4 atomic chains in flight;
//     R1 showed fill_csr 141us @ VALUBusy 0.4% = pure latency);
//     (b) h stored as bf16 -> halves the per-edge 512B row gather;
//     (c) agg lane remap: lane owns 2 adjacent channels -> 1 gather + 1 exp
//     per lane per edge; edge loop unrolled x8.

typedef unsigned short bfu;

constexpr int N_NODES = 100000;
constexpr int E_IN    = 1600000;
constexpr int E_TOT   = E_IN + N_NODES;   // + self loops
constexpr float NEG   = 0.2f;

__device__ inline float bf2f(bfu u) {
    union { unsigned i; float f; } c; c.i = ((unsigned)u) << 16; return c.f;
}
__device__ inline bfu f2bf(float f) {
    union { float f; unsigned i; } c; c.f = f;
    unsigned x = c.i;
    return (bfu)((x + 0x7fffu + ((x >> 16) & 1u)) >> 16);
}

// ---------------- CSR build ----------------

__global__ void count_deg(const int* __restrict__ ei, int* __restrict__ deg) {
    int e0 = (blockIdx.x * 256 + threadIdx.x) * 4;
    if (e0 >= E_TOT) return;
    int4 d4;
    if (e0 < E_IN) d4 = *(const int4*)&ei[E_IN + e0];
    else { int b = e0 - E_IN; d4 = make_int4(b, b + 1, b + 2, b + 3); }
    atomicAdd(&deg[d4.x], 1);
    atomicAdd(&deg[d4.y], 1);
    atomicAdd(&deg[d4.z], 1);
    atomicAdd(&deg[d4.w], 1);
}

__global__ void scan_partial(const int* __restrict__ deg, int* __restrict__ bsum) {
    __shared__ int lds[256];
    int i = blockIdx.x * 256 + threadIdx.x;
    int v = (i < N_NODES) ? deg[i] : 0;
    lds[threadIdx.x] = v;
    __syncthreads();
    for (int s = 128; s > 0; s >>= 1) {
        if (threadIdx.x < s) lds[threadIdx.x] += lds[threadIdx.x + s];
        __syncthreads();
    }
    if (threadIdx.x == 0) bsum[blockIdx.x] = lds[0];
}

__global__ void scan_bsums(const int* __restrict__ bsum, int* __restrict__ bofs,
                           int* __restrict__ rowptr, int nb) {
    int lane = threadIdx.x;  // 64 threads
    int carry = 0;
    for (int base = 0; base < nb; base += 64) {
        int i = base + lane;
        int v = (i < nb) ? bsum[i] : 0;
        int x = v;
        #pragma unroll
        for (int d = 1; d < 64; d <<= 1) {
            int y = __shfl_up(x, d);
            if (lane >= d) x += y;
        }
        int excl = x - v + carry;
        if (i < nb) bofs[i] = excl;
        carry += __shfl(x, 63);
    }
    if (lane == 0) rowptr[N_NODES] = carry;  // == E_TOT
}

__global__ void scan_write(const int* __restrict__ deg, const int* __restrict__ bofs,
                           int* __restrict__ rowptr, int* __restrict__ cursor) {
    __shared__ int a[256], b[256];
    int t = threadIdx.x;
    int i = blockIdx.x * 256 + t;
    int v = (i < N_NODES) ? deg[i] : 0;
    a[t] = v;
    __syncthreads();
    int* src = a; int* dst = b;
    for (int d = 1; d < 256; d <<= 1) {
        dst[t] = src[t] + ((t >= d) ? src[t - d] : 0);
        __syncthreads();
        int* tmp = src; src = dst; dst = tmp;
    }
    int excl = src[t] - v + bofs[blockIdx.x];
    if (i < N_NODES) { rowptr[i] = excl; cursor[i] = excl; }
}

__global__ void fill_csr(const int* __restrict__ ei, int* __restrict__ cursor,
                         int* __restrict__ srclist) {
    int e0 = (blockIdx.x * 256 + threadIdx.x) * 4;
    if (e0 >= E_TOT) return;
    int4 s4, d4;
    if (e0 < E_IN) { s4 = *(const int4*)&ei[e0]; d4 = *(const int4*)&ei[E_IN + e0]; }
    else { int b = e0 - E_IN; s4 = make_int4(b, b + 1, b + 2, b + 3); d4 = s4; }
    int p0 = atomicAdd(&cursor[d4.x], 1);
    int p1 = atomicAdd(&cursor[d4.y], 1);
    int p2 = atomicAdd(&cursor[d4.z], 1);
    int p3 = atomicAdd(&cursor[d4.w], 1);
    srclist[p0] = s4.x;
    srclist[p1] = s4.y;
    srclist[p2] = s4.z;
    srclist[p3] = s4.w;
}

// ---------------- GEMM: Y[N,COUT] = X[N,128] @ W[128,COUT], bf16 out --------

template<int COUT>
__global__ __launch_bounds__(256) void gemm_k(const float* __restrict__ X,
                                              const float* __restrict__ Wg,
                                              bfu* __restrict__ Y) {
    constexpr int CG  = COUT / 4;
    constexpr int RG  = 256 / CG;
    constexpr int RPT = (COUT == 128) ? 4 : 2;
    constexpr int RB  = RG * RPT;
    constexpr int KCH = (COUT == 128) ? 64 : 128;
    constexpr int XSTR = 132;

    __shared__ float Wl[KCH * COUT];
    __shared__ float Xl[RB * XSTR];

    int t = threadIdx.x;
    int rbase = blockIdx.x * RB;

    for (int i = t; i < RB * 32; i += 256) {
        int r = i >> 5, c4 = i & 31;
        int gr = rbase + r; if (gr >= N_NODES) gr = N_NODES - 1;
        *(float4*)&Xl[r * XSTR + c4 * 4] = *(const float4*)&X[gr * 128 + c4 * 4];
    }

    int cg = t % CG, rg = t / CG;
    int c0 = cg * 4, r0 = rg * RPT;
    float4 acc[RPT];
    #pragma unroll
    for (int i = 0; i < RPT; i++) acc[i] = make_float4(0.f, 0.f, 0.f, 0.f);

    for (int ph = 0; ph < 128 / KCH; ++ph) {
        __syncthreads();
        for (int i = t * 4; i < KCH * COUT; i += 1024)
            *(float4*)&Wl[i] = *(const float4*)&Wg[ph * KCH * COUT + i];
        __syncthreads();
        for (int k4 = 0; k4 < KCH / 4; ++k4) {
            int kb = ph * KCH + k4 * 4;
            float4 wv[4], xv[RPT];
            #pragma unroll
            for (int kk = 0; kk < 4; kk++) wv[kk] = *(float4*)&Wl[(k4 * 4 + kk) * COUT + c0];
            #pragma unroll
            for (int i = 0; i < RPT; i++) xv[i] = *(float4*)&Xl[(r0 + i) * XSTR + kb];
            #pragma unroll
            for (int i = 0; i < RPT; i++) {
                const float* xs = (const float*)&xv[i];
                #pragma unroll
                for (int kk = 0; kk < 4; kk++) {
                    acc[i].x += xs[kk] * wv[kk].x;
                    acc[i].y += xs[kk] * wv[kk].y;
                    acc[i].z += xs[kk] * wv[kk].z;
                    acc[i].w += xs[kk] * wv[kk].w;
                }
            }
        }
    }
    #pragma unroll
    for (int i = 0; i < RPT; i++) {
        int gr = rbase + r0 + i;
        if (gr < N_NODES) {
            ushort4 o;
            o.x = f2bf(acc[i].x); o.y = f2bf(acc[i].y);
            o.z = f2bf(acc[i].z); o.w = f2bf(acc[i].w);
            *(ushort4*)&Y[(size_t)gr * COUT + c0] = o;
        }
    }
}

// ---------------- per-node logit parts (bf16 h) ----------------

template<int H, int HID>
__global__ void logits_k(const bfu* __restrict__ Hb, const float* __restrict__ a_src,
                         const float* __restrict__ a_dst,
                         float* __restrict__ als, float* __restrict__ ald) {
    int id = blockIdx.x * 256 + threadIdx.x;
    if (id >= N_NODES * H) return;
    int n = id / H, h = id % H;
    const bfu* row = &Hb[(size_t)(n * H + h) * HID];
    float s = 0.f, dd = 0.f;
    #pragma unroll
    for (int j = 0; j < HID; j += 2) {
        unsigned u = *(const unsigned*)&row[j];
        float f0 = bf2f((bfu)(u & 0xffff)), f1 = bf2f((bfu)(u >> 16));
        s  += f0 * a_src[h * HID + j] + f1 * a_src[h * HID + j + 1];
        dd += f0 * a_dst[h * HID + j] + f1 * a_dst[h * HID + j + 1];
    }
    als[id] = s; ald[id] = dd;
}

// ---------------- aggregation ----------------
// agg128: one wave per dst; lane owns channels {2*lane, 2*lane+1} (same head
// h=lane>>3) -> one 4B gather + one exp per lane per edge. Unroll x8.

__global__ __launch_bounds__(256) void agg128(const bfu* __restrict__ Hb,
        const float* __restrict__ als, const float* __restrict__ ald,
        const int* __restrict__ rowptr, const int* __restrict__ srclist,
        const float* __restrict__ bias, float* __restrict__ out) {
    int wave = (blockIdx.x * 256 + threadIdx.x) >> 6;
    int lane = threadIdx.x & 63;
    if (wave >= N_NODES) return;
    int d = wave;
    int c0 = lane * 2;
    int h = lane >> 3;
    float ad = ald[d * 8 + h];
    float accx = 0.f, accy = 0.f, den = 0.f;
    int beg = rowptr[d], end = rowptr[d + 1];
    int j = beg;
    for (; j + 8 <= end; j += 8) {
        int s0 = srclist[j+0], s1 = srclist[j+1], s2 = srclist[j+2], s3 = srclist[j+3];
        int s4 = srclist[j+4], s5 = srclist[j+5], s6 = srclist[j+6], s7 = srclist[j+7];
        unsigned u0 = *(const unsigned*)&Hb[(size_t)s0 * 128 + c0];
        unsigned u1 = *(const unsigned*)&Hb[(size_t)s1 * 128 + c0];
        unsigned u2 = *(const unsigned*)&Hb[(size_t)s2 * 128 + c0];
        unsigned u3 = *(const unsigned*)&Hb[(size_t)s3 * 128 + c0];
        unsigned u4 = *(const unsigned*)&Hb[(size_t)s4 * 128 + c0];
        unsigned u5 = *(const unsigned*)&Hb[(size_t)s5 * 128 + c0];
        unsigned u6 = *(const unsigned*)&Hb[(size_t)s6 * 128 + c0];
        unsigned u7 = *(const unsigned*)&Hb[(size_t)s7 * 128 + c0];
        float x0 = als[s0*8+h], x1 = als[s1*8+h], x2 = als[s2*8+h], x3 = als[s3*8+h];
        float x4 = als[s4*8+h], x5 = als[s5*8+h], x6 = als[s6*8+h], x7 = als[s7*8+h];
        float l, w;
        l = x0 + ad; l = fmaxf(l, NEG*l); w = __expf(l); den += w;
        accx = fmaf(w, bf2f((bfu)(u0 & 0xffff)), accx); accy = fmaf(w, bf2f((bfu)(u0 >> 16)), accy);
        l = x1 + ad; l = fmaxf(l, NEG*l); w = __expf(l); den += w;
        accx = fmaf(w, bf2f((bfu)(u1 & 0xffff)), accx); accy = fmaf(w, bf2f((bfu)(u1 >> 16)), accy);
        l = x2 + ad; l = fmaxf(l, NEG*l); w = __expf(l); den += w;
        accx = fmaf(w, bf2f((bfu)(u2 & 0xffff)), accx); accy = fmaf(w, bf2f((bfu)(u2 >> 16)), accy);
        l = x3 + ad; l = fmaxf(l, NEG*l); w = __expf(l); den += w;
        accx = fmaf(w, bf2f((bfu)(u3 & 0xffff)), accx); accy = fmaf(w, bf2f((bfu)(u3 >> 16)), accy);
        l = x4 + ad; l = fmaxf(l, NEG*l); w = __expf(l); den += w;
        accx = fmaf(w, bf2f((bfu)(u4 & 0xffff)), accx); accy = fmaf(w, bf2f((bfu)(u4 >> 16)), accy);
        l = x5 + ad; l = fmaxf(l, NEG*l); w = __expf(l); den += w;
        accx = fmaf(w, bf2f((bfu)(u5 & 0xffff)), accx); accy = fmaf(w, bf2f((bfu)(u5 >> 16)), accy);
        l = x6 + ad; l = fmaxf(l, NEG*l); w = __expf(l); den += w;
        accx = fmaf(w, bf2f((bfu)(u6 & 0xffff)), accx); accy = fmaf(w, bf2f((bfu)(u6 >> 16)), accy);
        l = x7 + ad; l = fmaxf(l, NEG*l); w = __expf(l); den += w;
        accx = fmaf(w, bf2f((bfu)(u7 & 0xffff)), accx); accy = fmaf(w, bf2f((bfu)(u7 >> 16)), accy);
    }
    for (; j < end; ++j) {
        int s = srclist[j];
        unsigned u = *(const unsigned*)&Hb[(size_t)s * 128 + c0];
        float l = als[s*8+h] + ad; l = fmaxf(l, NEG*l);
        float w = __expf(l); den += w;
        accx = fmaf(w, bf2f((bfu)(u & 0xffff)), accx);
        accy = fmaf(w, bf2f((bfu)(u >> 16)), accy);
    }
    float rden = 1.f / den;
    float ox = accx * rden + bias[c0];     ox = ox > 0.f ? ox : 0.f;
    float oy = accy * rden + bias[c0 + 1]; oy = oy > 0.f ? oy : 0.f;
    *(float2*)&out[(size_t)d * 128 + c0] = make_float2(ox, oy);
}

// agg32: 4 dst nodes per wave (16 lanes x 2ch each), H=1, no relu.
__global__ __launch_bounds__(256) void agg32(const bfu* __restrict__ Hb,
        const float* __restrict__ als, const float* __restrict__ ald,
        const int* __restrict__ rowptr, const int* __restrict__ srclist,
        const float* __restrict__ bias, float* __restrict__ out) {
    int wave = (blockIdx.x * 256 + threadIdx.x) >> 6;
    int lane = threadIdx.x & 63;
    int d = wave * 4 + (lane >> 4);
    int c0 = (lane & 15) * 2;
    if (d >= N_NODES) return;
    float adv = ald[d];
    float accx = 0.f, accy = 0.f, den = 0.f;
    int beg = rowptr[d], end = rowptr[d + 1];
    int j = beg;
    for (; j + 4 <= end; j += 4) {
        int s0 = srclist[j+0], s1 = srclist[j+1], s2 = srclist[j+2], s3 = srclist[j+3];
        unsigned u0 = *(const unsigned*)&Hb[(size_t)s0 * 32 + c0];
        unsigned u1 = *(const unsigned*)&Hb[(size_t)s1 * 32 + c0];
        unsigned u2 = *(const unsigned*)&Hb[(size_t)s2 * 32 + c0];
        unsigned u3 = *(const unsigned*)&Hb[(size_t)s3 * 32 + c0];
        float x0 = als[s0], x1 = als[s1], x2 = als[s2], x3 = als[s3];
        float l, w;
        l = x0 + adv; l = fmaxf(l, NEG*l); w = __expf(l); den += w;
        accx = fmaf(w, bf2f((bfu)(u0 & 0xffff)), accx); accy = fmaf(w, bf2f((bfu)(u0 >> 16)), accy);
        l = x1 + adv; l = fmaxf(l, NEG*l); w = __expf(l); den += w;
        accx = fmaf(w, bf2f((bfu)(u1 & 0xffff)), accx); accy = fmaf(w, bf2f((bfu)(u1 >> 16)), accy);
        l = x2 + adv; l = fmaxf(l, NEG*l); w = __expf(l); den += w;
        accx = fmaf(w, bf2f((bfu)(u2 & 0xffff)), accx); accy = fmaf(w, bf2f((bfu)(u2 >> 16)), accy);
        l = x3 + adv; l = fmaxf(l, NEG*l); w = __expf(l); den += w;
        accx = fmaf(w, bf2f((bfu)(u3 & 0xffff)), accx); accy = fmaf(w, bf2f((bfu)(u3 >> 16)), accy);
    }
    for (; j < end; ++j) {
        int s = srclist[j];
        unsigned u = *(const unsigned*)&Hb[(size_t)s * 32 + c0];
        float l = als[s] + adv; l = fmaxf(l, NEG*l);
        float w = __expf(l); den += w;
        accx = fmaf(w, bf2f((bfu)(u & 0xffff)), accx);
        accy = fmaf(w, bf2f((bfu)(u >> 16)), accy);
    }
    float rden = 1.f / den;
    float ox = accx * rden + bias[c0];
    float oy = accy * rden + bias[c0 + 1];
    *(float2*)&out[(size_t)d * 32 + c0] = make_float2(ox, oy);
}

// ---------------- global mean pool ----------------
__global__ void pool32(const float* __restrict__ h3, float* __restrict__ outp) {
    __shared__ float lds[256];
    int t = threadIdx.x;
    int c = t & 31, g = t >> 5;
    float acc = 0.f;
    for (int n = blockIdx.x * 8 + g; n < N_NODES; n += gridDim.x * 8)
        acc += h3[n * 32 + c];
    lds[t] = acc;
    __syncthreads();
    if (g == 0) {
        float s = 0.f;
        for (int gg = 0; gg < 8; ++gg) s += lds[gg * 32 + c];
        atomicAdd(&outp[c], s * (1.0f / N_NODES));
    }
}

// ---------------- launch ----------------

extern "C" void kernel_launch(void* const* d_in, const int* in_sizes, int n_in,
                              void* d_out, int out_size, void* d_ws, size_t ws_size,
                              hipStream_t stream) {
    (void)in_sizes; (void)n_in; (void)out_size; (void)ws_size;
    const float* x   = (const float*)d_in[0];
    const int*   ei  = (const int*)d_in[1];
    const float* W1  = (const float*)d_in[2];
    const float* as1 = (const float*)d_in[3];
    const float* ad1 = (const float*)d_in[4];
    const float* b1  = (const float*)d_in[5];
    const float* W2  = (const float*)d_in[6];
    const float* as2 = (const float*)d_in[7];
    const float* ad2 = (const float*)d_in[8];
    const float* b2  = (const float*)d_in[9];
    const float* W3  = (const float*)d_in[10];
    const float* as3 = (const float*)d_in[11];
    const float* ad3 = (const float*)d_in[12];
    const float* b3  = (const float*)d_in[13];

    char* ws = (char*)d_ws;
    size_t off = 0;
    auto carve = [&](size_t bytes) { void* p = ws + off; off += (bytes + 255) & ~size_t(255); return p; };
    bfu*   bufH    = (bfu*)carve(size_t(N_NODES) * 128 * 2);    // h = X@W (bf16)
    float* bufF    = (float*)carve(size_t(N_NODES) * 128 * 4);  // agg out (fp32)
    float* als     = (float*)carve(size_t(N_NODES) * 8 * 4);
    float* ald     = (float*)carve(size_t(N_NODES) * 8 * 4);
    int*   deg     = (int*)carve(size_t(N_NODES) * 4);
    int*   rowptr  = (int*)carve(size_t(N_NODES + 1) * 4);
    int*   cursor  = (int*)carve(size_t(N_NODES) * 4);
    int*   bsum    = (int*)carve(512 * 4);
    int*   bofs    = (int*)carve(512 * 4);
    int*   srclist = (int*)carve(size_t(E_TOT) * 4);

    const int SCAN_B  = (N_NODES + 255) / 256;
    const int EDGE_B4 = (E_TOT / 4 + 255) / 256;

    hipMemsetAsync(deg, 0, size_t(N_NODES) * 4, stream);
    hipMemsetAsync(d_out, 0, 32 * 4, stream);

    count_deg  <<<EDGE_B4, 256, 0, stream>>>(ei, deg);
    scan_partial<<<SCAN_B, 256, 0, stream>>>(deg, bsum);
    scan_bsums <<<1, 64, 0, stream>>>(bsum, bofs, rowptr, SCAN_B);
    scan_write <<<SCAN_B, 256, 0, stream>>>(deg, bofs, rowptr, cursor);
    fill_csr   <<<EDGE_B4, 256, 0, stream>>>(ei, cursor, srclist);

    gemm_k<128><<<N_NODES / 32, 256, 0, stream>>>(x, W1, bufH);
    logits_k<8, 16><<<(N_NODES * 8 + 255) / 256, 256, 0, stream>>>(bufH, as1, ad1, als, ald);
    agg128<<<(N_NODES + 3) / 4, 256, 0, stream>>>(bufH, als, ald, rowptr, srclist, b1, bufF);

    gemm_k<128><<<N_NODES / 32, 256, 0, stream>>>(bufF, W2, bufH);
    logits_k<8, 16><<<(N_NODES * 8 + 255) / 256, 256, 0, stream>>>(bufH, as2, ad2, als, ald);
    agg128<<<(N_NODES + 3) / 4, 256, 0, stream>>>(bufH, als, ald, rowptr, srclist, b2, bufF);

    gemm_k<32><<<(N_NODES + 63) / 64, 256, 0, stream>>>(bufF, W3, bufH);
    logits_k<1, 32><<<(N_NODES + 255) / 256, 256, 0, stream>>>(bufH, as3, ad3, als, ald);
    agg32<<<(N_NODES / 4 + 3) / 4, 256, 0, stream>>>(bufH, als, ald, rowptr, srclist, b3, bufF);
    pool32<<<64, 256, 0, stream>>>(bufF, (float*)d_out);
}

// Round 4
// 685.321 us; speedup vs baseline: 1.2487x; 1.2487x over previous
//
#include <hip/hip_runtime.h>

// GAT (3-layer) on MI355X.
// R3: replace fp32 vector GEMM (158us, VGPR=244, occupancy 11% -- register
// cliff) with MFMA bf16 GEMM using verified gfx950 fragment layouts:
//   A[m=lane&15][k=quad*8+j], B^T-input (Wt[n][k] contiguous 16B frags),
//   C/D row=quad*4+reg, col=lane&15.  No LDS; Wt (32KB) sits in L1/L2.
// agg128 emits bf16 so layers 2/3 feed MFMA natively.

typedef unsigned short bfu;
typedef __attribute__((ext_vector_type(8))) short bf16x8;
typedef __attribute__((ext_vector_type(4))) float f32x4;

constexpr int N_NODES = 100000;
constexpr int E_IN    = 1600000;
constexpr int E_TOT   = E_IN + N_NODES;   // + self loops
constexpr float NEG   = 0.2f;

__device__ inline float bf2f(bfu u) {
    union { unsigned i; float f; } c; c.i = ((unsigned)u) << 16; return c.f;
}
__device__ inline bfu f2bf(float f) {
    union { float f; unsigned i; } c; c.f = f;
    unsigned x = c.i;
    return (bfu)((x + 0x7fffu + ((x >> 16) & 1u)) >> 16);
}

// ---------------- CSR build ----------------

__global__ void count_deg(const int* __restrict__ ei, int* __restrict__ deg) {
    int e0 = (blockIdx.x * 256 + threadIdx.x) * 4;
    if (e0 >= E_TOT) return;
    int4 d4;
    if (e0 < E_IN) d4 = *(const int4*)&ei[E_IN + e0];
    else { int b = e0 - E_IN; d4 = make_int4(b, b + 1, b + 2, b + 3); }
    atomicAdd(&deg[d4.x], 1);
    atomicAdd(&deg[d4.y], 1);
    atomicAdd(&deg[d4.z], 1);
    atomicAdd(&deg[d4.w], 1);
}

__global__ void scan_partial(const int* __restrict__ deg, int* __restrict__ bsum) {
    __shared__ int lds[256];
    int i = blockIdx.x * 256 + threadIdx.x;
    int v = (i < N_NODES) ? deg[i] : 0;
    lds[threadIdx.x] = v;
    __syncthreads();
    for (int s = 128; s > 0; s >>= 1) {
        if (threadIdx.x < s) lds[threadIdx.x] += lds[threadIdx.x + s];
        __syncthreads();
    }
    if (threadIdx.x == 0) bsum[blockIdx.x] = lds[0];
}

__global__ void scan_bsums(const int* __restrict__ bsum, int* __restrict__ bofs,
                           int* __restrict__ rowptr, int nb) {
    int lane = threadIdx.x;  // 64 threads
    int carry = 0;
    for (int base = 0; base < nb; base += 64) {
        int i = base + lane;
        int v = (i < nb) ? bsum[i] : 0;
        int x = v;
        #pragma unroll
        for (int d = 1; d < 64; d <<= 1) {
            int y = __shfl_up(x, d);
            if (lane >= d) x += y;
        }
        int excl = x - v + carry;
        if (i < nb) bofs[i] = excl;
        carry += __shfl(x, 63);
    }
    if (lane == 0) rowptr[N_NODES] = carry;  // == E_TOT
}

__global__ void scan_write(const int* __restrict__ deg, const int* __restrict__ bofs,
                           int* __restrict__ rowptr, int* __restrict__ cursor) {
    __shared__ int a[256], b[256];
    int t = threadIdx.x;
    int i = blockIdx.x * 256 + t;
    int v = (i < N_NODES) ? deg[i] : 0;
    a[t] = v;
    __syncthreads();
    int* src = a; int* dst = b;
    for (int d = 1; d < 256; d <<= 1) {
        dst[t] = src[t] + ((t >= d) ? src[t - d] : 0);
        __syncthreads();
        int* tmp = src; src = dst; dst = tmp;
    }
    int excl = src[t] - v + bofs[blockIdx.x];
    if (i < N_NODES) { rowptr[i] = excl; cursor[i] = excl; }
}

__global__ void fill_csr(const int* __restrict__ ei, int* __restrict__ cursor,
                         int* __restrict__ srclist) {
    int e0 = (blockIdx.x * 256 + threadIdx.x) * 4;
    if (e0 >= E_TOT) return;
    int4 s4, d4;
    if (e0 < E_IN) { s4 = *(const int4*)&ei[e0]; d4 = *(const int4*)&ei[E_IN + e0]; }
    else { int b = e0 - E_IN; s4 = make_int4(b, b + 1, b + 2, b + 3); d4 = s4; }
    int p0 = atomicAdd(&cursor[d4.x], 1);
    int p1 = atomicAdd(&cursor[d4.y], 1);
    int p2 = atomicAdd(&cursor[d4.z], 1);
    int p3 = atomicAdd(&cursor[d4.w], 1);
    srclist[p0] = s4.x;
    srclist[p1] = s4.y;
    srclist[p2] = s4.z;
    srclist[p3] = s4.w;
}

// ---------------- prep: x -> bf16, W -> W^T bf16 ----------------

__global__ void convert_x(const float* __restrict__ x, bfu* __restrict__ xb) {
    int i = (blockIdx.x * 256 + threadIdx.x) * 4;
    if (i >= N_NODES * 128) return;
    float4 v = *(const float4*)&x[i];
    ushort4 o;
    o.x = f2bf(v.x); o.y = f2bf(v.y); o.z = f2bf(v.z); o.w = f2bf(v.w);
    *(ushort4*)&xb[i] = o;
}

// W1[128,128], W2[128,128], W3[128,32] fp32 -> Wt[n][k] bf16 (each k-stride 128)
__global__ void transpose_w(const float* __restrict__ W1, const float* __restrict__ W2,
                            const float* __restrict__ W3,
                            bfu* __restrict__ Wt1, bfu* __restrict__ Wt2,
                            bfu* __restrict__ Wt3) {
    int idx = blockIdx.x * 256 + threadIdx.x;
    if (idx < 16384) {
        int k = idx >> 7, n = idx & 127;
        Wt1[n * 128 + k] = f2bf(W1[idx]);
    } else if (idx < 32768) {
        int r = idx - 16384;
        int k = r >> 7, n = r & 127;
        Wt2[n * 128 + k] = f2bf(W2[r]);
    } else if (idx < 32768 + 4096) {
        int r = idx - 32768;
        int k = r >> 5, n = r & 31;
        Wt3[n * 128 + k] = f2bf(W3[r]);
    }
}

// ---------------- MFMA GEMM: Y[N,COUT](bf16) = X[N,128](bf16) @ W ----------
// One wave per 16 rows; B via pre-transposed Wt[n][k] (contiguous 16B frags).

template<int COUT>
__global__ __launch_bounds__(256) void gemm_mfma(const bfu* __restrict__ Xg,
                                                 const bfu* __restrict__ Wt,
                                                 bfu* __restrict__ Y) {
    constexpr int NT = COUT / 16;
    int wid  = threadIdx.x >> 6;
    int lane = threadIdx.x & 63;
    int m = lane & 15, quad = lane >> 4;
    int rbase = (blockIdx.x * 4 + wid) * 16;
    if (rbase >= N_NODES) return;
    int rA = rbase + m; if (rA >= N_NODES) rA = N_NODES - 1;

    const bfu* Ap = Xg + (size_t)rA * 128 + quad * 8;
    bf16x8 a0 = *(const bf16x8*)(Ap);
    bf16x8 a1 = *(const bf16x8*)(Ap + 32);
    bf16x8 a2 = *(const bf16x8*)(Ap + 64);
    bf16x8 a3 = *(const bf16x8*)(Ap + 96);

    const bfu* Bp = Wt + (size_t)m * 128 + quad * 8;   // lane&15 indexes n
    f32x4 acc[NT];
    #pragma unroll
    for (int nt = 0; nt < NT; nt++) {
        const bfu* Bn = Bp + nt * 16 * 128;
        f32x4 c = {0.f, 0.f, 0.f, 0.f};
        c = __builtin_amdgcn_mfma_f32_16x16x32_bf16(a0, *(const bf16x8*)(Bn),      c, 0, 0, 0);
        c = __builtin_amdgcn_mfma_f32_16x16x32_bf16(a1, *(const bf16x8*)(Bn + 32), c, 0, 0, 0);
        c = __builtin_amdgcn_mfma_f32_16x16x32_bf16(a2, *(const bf16x8*)(Bn + 64), c, 0, 0, 0);
        c = __builtin_amdgcn_mfma_f32_16x16x32_bf16(a3, *(const bf16x8*)(Bn + 96), c, 0, 0, 0);
        acc[nt] = c;
    }
    #pragma unroll
    for (int nt = 0; nt < NT; nt++) {
        #pragma unroll
        for (int r = 0; r < 4; r++) {
            int row = rbase + quad * 4 + r;
            if (row < N_NODES)
                Y[(size_t)row * COUT + nt * 16 + m] = f2bf(acc[nt][r]);
        }
    }
}

// ---------------- per-node logit parts (bf16 h) ----------------

template<int H, int HID>
__global__ void logits_k(const bfu* __restrict__ Hb, const float* __restrict__ a_src,
                         const float* __restrict__ a_dst,
                         float* __restrict__ als, float* __restrict__ ald) {
    int id = blockIdx.x * 256 + threadIdx.x;
    if (id >= N_NODES * H) return;
    int n = id / H, h = id % H;
    const bfu* row = &Hb[(size_t)(n * H + h) * HID];
    float s = 0.f, dd = 0.f;
    #pragma unroll
    for (int j = 0; j < HID; j += 2) {
        unsigned u = *(const unsigned*)&row[j];
        float f0 = bf2f((bfu)(u & 0xffff)), f1 = bf2f((bfu)(u >> 16));
        s  += f0 * a_src[h * HID + j] + f1 * a_src[h * HID + j + 1];
        dd += f0 * a_dst[h * HID + j] + f1 * a_dst[h * HID + j + 1];
    }
    als[id] = s; ald[id] = dd;
}

// ---------------- aggregation ----------------
// agg128: one wave per dst; lane owns channels {2*lane, 2*lane+1} (head
// h=lane>>3) -> one 4B gather + one exp per lane per edge. Unroll x8.
// Output bf16 (feeds next MFMA GEMM).

__global__ __launch_bounds__(256) void agg128(const bfu* __restrict__ Hb,
        const float* __restrict__ als, const float* __restrict__ ald,
        const int* __restrict__ rowptr, const int* __restrict__ srclist,
        const float* __restrict__ bias, bfu* __restrict__ out) {
    int wave = (blockIdx.x * 256 + threadIdx.x) >> 6;
    int lane = threadIdx.x & 63;
    if (wave >= N_NODES) return;
    int d = wave;
    int c0 = lane * 2;
    int h = lane >> 3;
    float ad = ald[d * 8 + h];
    float accx = 0.f, accy = 0.f, den = 0.f;
    int beg = rowptr[d], end = rowptr[d + 1];
    int j = beg;
    for (; j + 8 <= end; j += 8) {
        int s0 = srclist[j+0], s1 = srclist[j+1], s2 = srclist[j+2], s3 = srclist[j+3];
        int s4 = srclist[j+4], s5 = srclist[j+5], s6 = srclist[j+6], s7 = srclist[j+7];
        unsigned u0 = *(const unsigned*)&Hb[(size_t)s0 * 128 + c0];
        unsigned u1 = *(const unsigned*)&Hb[(size_t)s1 * 128 + c0];
        unsigned u2 = *(const unsigned*)&Hb[(size_t)s2 * 128 + c0];
        unsigned u3 = *(const unsigned*)&Hb[(size_t)s3 * 128 + c0];
        unsigned u4 = *(const unsigned*)&Hb[(size_t)s4 * 128 + c0];
        unsigned u5 = *(const unsigned*)&Hb[(size_t)s5 * 128 + c0];
        unsigned u6 = *(const unsigned*)&Hb[(size_t)s6 * 128 + c0];
        unsigned u7 = *(const unsigned*)&Hb[(size_t)s7 * 128 + c0];
        float x0 = als[s0*8+h], x1 = als[s1*8+h], x2 = als[s2*8+h], x3 = als[s3*8+h];
        float x4 = als[s4*8+h], x5 = als[s5*8+h], x6 = als[s6*8+h], x7 = als[s7*8+h];
        float l, w;
        l = x0 + ad; l = fmaxf(l, NEG*l); w = __expf(l); den += w;
        accx = fmaf(w, bf2f((bfu)(u0 & 0xffff)), accx); accy = fmaf(w, bf2f((bfu)(u0 >> 16)), accy);
        l = x1 + ad; l = fmaxf(l, NEG*l); w = __expf(l); den += w;
        accx = fmaf(w, bf2f((bfu)(u1 & 0xffff)), accx); accy = fmaf(w, bf2f((bfu)(u1 >> 16)), accy);
        l = x2 + ad; l = fmaxf(l, NEG*l); w = __expf(l); den += w;
        accx = fmaf(w, bf2f((bfu)(u2 & 0xffff)), accx); accy = fmaf(w, bf2f((bfu)(u2 >> 16)), accy);
        l = x3 + ad; l = fmaxf(l, NEG*l); w = __expf(l); den += w;
        accx = fmaf(w, bf2f((bfu)(u3 & 0xffff)), accx); accy = fmaf(w, bf2f((bfu)(u3 >> 16)), accy);
        l = x4 + ad; l = fmaxf(l, NEG*l); w = __expf(l); den += w;
        accx = fmaf(w, bf2f((bfu)(u4 & 0xffff)), accx); accy = fmaf(w, bf2f((bfu)(u4 >> 16)), accy);
        l = x5 + ad; l = fmaxf(l, NEG*l); w = __expf(l); den += w;
        accx = fmaf(w, bf2f((bfu)(u5 & 0xffff)), accx); accy = fmaf(w, bf2f((bfu)(u5 >> 16)), accy);
        l = x6 + ad; l = fmaxf(l, NEG*l); w = __expf(l); den += w;
        accx = fmaf(w, bf2f((bfu)(u6 & 0xffff)), accx); accy = fmaf(w, bf2f((bfu)(u6 >> 16)), accy);
        l = x7 + ad; l = fmaxf(l, NEG*l); w = __expf(l); den += w;
        accx = fmaf(w, bf2f((bfu)(u7 & 0xffff)), accx); accy = fmaf(w, bf2f((bfu)(u7 >> 16)), accy);
    }
    for (; j < end; ++j) {
        int s = srclist[j];
        unsigned u = *(const unsigned*)&Hb[(size_t)s * 128 + c0];
        float l = als[s*8+h] + ad; l = fmaxf(l, NEG*l);
        float w = __expf(l); den += w;
        accx = fmaf(w, bf2f((bfu)(u & 0xffff)), accx);
        accy = fmaf(w, bf2f((bfu)(u >> 16)), accy);
    }
    float rden = 1.f / den;
    float ox = accx * rden + bias[c0];     ox = ox > 0.f ? ox : 0.f;
    float oy = accy * rden + bias[c0 + 1]; oy = oy > 0.f ? oy : 0.f;
    ushort2 o; o.x = f2bf(ox); o.y = f2bf(oy);
    *(ushort2*)&out[(size_t)d * 128 + c0] = o;
}

// agg32: 4 dst nodes per wave (16 lanes x 2ch each), H=1, no relu, fp32 out.
__global__ __launch_bounds__(256) void agg32(const bfu* __restrict__ Hb,
        const float* __restrict__ als, const float* __restrict__ ald,
        const int* __restrict__ rowptr, const int* __restrict__ srclist,
        const float* __restrict__ bias, float* __restrict__ out) {
    int wave = (blockIdx.x * 256 + threadIdx.x) >> 6;
    int lane = threadIdx.x & 63;
    int d = wave * 4 + (lane >> 4);
    int c0 = (lane & 15) * 2;
    if (d >= N_NODES) return;
    float adv = ald[d];
    float accx = 0.f, accy = 0.f, den = 0.f;
    int beg = rowptr[d], end = rowptr[d + 1];
    int j = beg;
    for (; j + 4 <= end; j += 4) {
        int s0 = srclist[j+0], s1 = srclist[j+1], s2 = srclist[j+2], s3 = srclist[j+3];
        unsigned u0 = *(const unsigned*)&Hb[(size_t)s0 * 32 + c0];
        unsigned u1 = *(const unsigned*)&Hb[(size_t)s1 * 32 + c0];
        unsigned u2 = *(const unsigned*)&Hb[(size_t)s2 * 32 + c0];
        unsigned u3 = *(const unsigned*)&Hb[(size_t)s3 * 32 + c0];
        float x0 = als[s0], x1 = als[s1], x2 = als[s2], x3 = als[s3];
        float l, w;
        l = x0 + adv; l = fmaxf(l, NEG*l); w = __expf(l); den += w;
        accx = fmaf(w, bf2f((bfu)(u0 & 0xffff)), accx); accy = fmaf(w, bf2f((bfu)(u0 >> 16)), accy);
        l = x1 + adv; l = fmaxf(l, NEG*l); w = __expf(l); den += w;
        accx = fmaf(w, bf2f((bfu)(u1 & 0xffff)), accx); accy = fmaf(w, bf2f((bfu)(u1 >> 16)), accy);
        l = x2 + adv; l = fmaxf(l, NEG*l); w = __expf(l); den += w;
        accx = fmaf(w, bf2f((bfu)(u2 & 0xffff)), accx); accy = fmaf(w, bf2f((bfu)(u2 >> 16)), accy);
        l = x3 + adv; l = fmaxf(l, NEG*l); w = __expf(l); den += w;
        accx = fmaf(w, bf2f((bfu)(u3 & 0xffff)), accx); accy = fmaf(w, bf2f((bfu)(u3 >> 16)), accy);
    }
    for (; j < end; ++j) {
        int s = srclist[j];
        unsigned u = *(const unsigned*)&Hb[(size_t)s * 32 + c0];
        float l = als[s] + adv; l = fmaxf(l, NEG*l);
        float w = __expf(l); den += w;
        accx = fmaf(w, bf2f((bfu)(u & 0xffff)), accx);
        accy = fmaf(w, bf2f((bfu)(u >> 16)), accy);
    }
    float rden = 1.f / den;
    float ox = accx * rden + bias[c0];
    float oy = accy * rden + bias[c0 + 1];
    *(float2*)&out[(size_t)d * 32 + c0] = make_float2(ox, oy);
}

// ---------------- global mean pool ----------------
__global__ void pool32(const float* __restrict__ h3, float* __restrict__ outp) {
    __shared__ float lds[256];
    int t = threadIdx.x;
    int c = t & 31, g = t >> 5;
    float acc = 0.f;
    for (int n = blockIdx.x * 8 + g; n < N_NODES; n += gridDim.x * 8)
        acc += h3[n * 32 + c];
    lds[t] = acc;
    __syncthreads();
    if (g == 0) {
        float s = 0.f;
        for (int gg = 0; gg < 8; ++gg) s += lds[gg * 32 + c];
        atomicAdd(&outp[c], s * (1.0f / N_NODES));
    }
}

// ---------------- launch ----------------

extern "C" void kernel_launch(void* const* d_in, const int* in_sizes, int n_in,
                              void* d_out, int out_size, void* d_ws, size_t ws_size,
                              hipStream_t stream) {
    (void)in_sizes; (void)n_in; (void)out_size; (void)ws_size;
    const float* x   = (const float*)d_in[0];
    const int*   ei  = (const int*)d_in[1];
    const float* W1  = (const float*)d_in[2];
    const float* as1 = (const float*)d_in[3];
    const float* ad1 = (const float*)d_in[4];
    const float* b1  = (const float*)d_in[5];
    const float* W2  = (const float*)d_in[6];
    const float* as2 = (const float*)d_in[7];
    const float* ad2 = (const float*)d_in[8];
    const float* b2  = (const float*)d_in[9];
    const float* W3  = (const float*)d_in[10];
    const float* as3 = (const float*)d_in[11];
    const float* ad3 = (const float*)d_in[12];
    const float* b3  = (const float*)d_in[13];

    char* ws = (char*)d_ws;
    size_t off = 0;
    auto carve = [&](size_t bytes) { void* p = ws + off; off += (bytes + 255) & ~size_t(255); return p; };
    bfu*   bufX    = (bfu*)carve(size_t(N_NODES) * 128 * 2);    // x in bf16
    bfu*   bufH    = (bfu*)carve(size_t(N_NODES) * 128 * 2);    // h = X@W (bf16)
    bfu*   bufF    = (bfu*)carve(size_t(N_NODES) * 128 * 2);    // agg out (bf16)
    float* out3    = (float*)carve(size_t(N_NODES) * 32 * 4);   // layer-3 agg (fp32)
    float* als     = (float*)carve(size_t(N_NODES) * 8 * 4);
    float* ald     = (float*)carve(size_t(N_NODES) * 8 * 4);
    int*   deg     = (int*)carve(size_t(N_NODES) * 4);
    int*   rowptr  = (int*)carve(size_t(N_NODES + 1) * 4);
    int*   cursor  = (int*)carve(size_t(N_NODES) * 4);
    int*   bsum    = (int*)carve(512 * 4);
    int*   bofs    = (int*)carve(512 * 4);
    bfu*   Wt1     = (bfu*)carve(128 * 128 * 2);
    bfu*   Wt2     = (bfu*)carve(128 * 128 * 2);
    bfu*   Wt3     = (bfu*)carve(32 * 128 * 2);
    int*   srclist = (int*)carve(size_t(E_TOT) * 4);

    const int SCAN_B  = (N_NODES + 255) / 256;
    const int EDGE_B4 = (E_TOT / 4 + 255) / 256;
    const int GEMM_B  = (N_NODES + 63) / 64;

    hipMemsetAsync(deg, 0, size_t(N_NODES) * 4, stream);
    hipMemsetAsync(d_out, 0, 32 * 4, stream);

    // prep
    convert_x  <<<(N_NODES * 128 / 4 + 255) / 256, 256, 0, stream>>>(x, bufX);
    transpose_w<<<(36864 + 255) / 256, 256, 0, stream>>>(W1, W2, W3, Wt1, Wt2, Wt3);

    // CSR build (graph shared by all 3 layers)
    count_deg  <<<EDGE_B4, 256, 0, stream>>>(ei, deg);
    scan_partial<<<SCAN_B, 256, 0, stream>>>(deg, bsum);
    scan_bsums <<<1, 64, 0, stream>>>(bsum, bofs, rowptr, SCAN_B);
    scan_write <<<SCAN_B, 256, 0, stream>>>(deg, bofs, rowptr, cursor);
    fill_csr   <<<EDGE_B4, 256, 0, stream>>>(ei, cursor, srclist);

    // layer 1
    gemm_mfma<128><<<GEMM_B, 256, 0, stream>>>(bufX, Wt1, bufH);
    logits_k<8, 16><<<(N_NODES * 8 + 255) / 256, 256, 0, stream>>>(bufH, as1, ad1, als, ald);
    agg128<<<(N_NODES + 3) / 4, 256, 0, stream>>>(bufH, als, ald, rowptr, srclist, b1, bufF);

    // layer 2
    gemm_mfma<128><<<GEMM_B, 256, 0, stream>>>(bufF, Wt2, bufH);
    logits_k<8, 16><<<(N_NODES * 8 + 255) / 256, 256, 0, stream>>>(bufH, as2, ad2, als, ald);
    agg128<<<(N_NODES + 3) / 4, 256, 0, stream>>>(bufH, als, ald, rowptr, srclist, b2, bufF);

    // layer 3
    gemm_mfma<32><<<GEMM_B, 256, 0, stream>>>(bufF, Wt3, bufH);
    logits_k<1, 32><<<(N_NODES + 255) / 256, 256, 0, stream>>>(bufH, as3, ad3, als, ald);
    agg32<<<(N_NODES / 4 + 3) / 4, 256, 0, stream>>>(bufH, als, ald, rowptr, srclist, b3, out3);
    pool32<<<64, 256, 0, stream>>>(out3, (float*)d_out);
}

// Round 5
// 628.071 us; speedup vs baseline: 1.3625x; 1.0912x over previous
//
#include <hip/hip_runtime.h>

// GAT (3-layer) on MI355X.
// R4: fill_csr rewritten as dst-partitioned scatter with XCD affinity
// (p = blockIdx.x & 7 -> XCD round-robin). R3 showed fill_csr 137us with
// WRITE_SIZE 110MB = 64B-line amplification on 4B scattered stores across
// 8 incoherent L2s. Partitioning gives each XCD a ~850KB L2-resident
// srclist window -> full lines, ~8MB writes.

typedef unsigned short bfu;
typedef __attribute__((ext_vector_type(8))) short bf16x8;
typedef __attribute__((ext_vector_type(4))) float f32x4;

constexpr int N_NODES = 100000;
constexpr int E_IN    = 1600000;
constexpr int E_TOT   = E_IN + N_NODES;   // + self loops (both divisible by 4)
constexpr float NEG   = 0.2f;
constexpr int P_XCD   = 8;
constexpr int PSZ     = N_NODES / P_XCD;  // 12500

__device__ inline float bf2f(bfu u) {
    union { unsigned i; float f; } c; c.i = ((unsigned)u) << 16; return c.f;
}
__device__ inline bfu f2bf(float f) {
    union { float f; unsigned i; } c; c.f = f;
    unsigned x = c.i;
    return (bfu)((x + 0x7fffu + ((x >> 16) & 1u)) >> 16);
}

// ---------------- CSR build ----------------

__global__ void count_deg(const int* __restrict__ ei, int* __restrict__ deg) {
    int e0 = (blockIdx.x * 256 + threadIdx.x) * 4;
    if (e0 >= E_TOT) return;
    int4 d4;
    if (e0 < E_IN) d4 = *(const int4*)&ei[E_IN + e0];
    else { int b = e0 - E_IN; d4 = make_int4(b, b + 1, b + 2, b + 3); }
    atomicAdd(&deg[d4.x], 1);
    atomicAdd(&deg[d4.y], 1);
    atomicAdd(&deg[d4.z], 1);
    atomicAdd(&deg[d4.w], 1);
}

__global__ void scan_partial(const int* __restrict__ deg, int* __restrict__ bsum) {
    __shared__ int lds[256];
    int i = blockIdx.x * 256 + threadIdx.x;
    int v = (i < N_NODES) ? deg[i] : 0;
    lds[threadIdx.x] = v;
    __syncthreads();
    for (int s = 128; s > 0; s >>= 1) {
        if (threadIdx.x < s) lds[threadIdx.x] += lds[threadIdx.x + s];
        __syncthreads();
    }
    if (threadIdx.x == 0) bsum[blockIdx.x] = lds[0];
}

__global__ void scan_bsums(const int* __restrict__ bsum, int* __restrict__ bofs,
                           int* __restrict__ rowptr, int nb) {
    int lane = threadIdx.x;  // 64 threads
    int carry = 0;
    for (int base = 0; base < nb; base += 64) {
        int i = base + lane;
        int v = (i < nb) ? bsum[i] : 0;
        int x = v;
        #pragma unroll
        for (int d = 1; d < 64; d <<= 1) {
            int y = __shfl_up(x, d);
            if (lane >= d) x += y;
        }
        int excl = x - v + carry;
        if (i < nb) bofs[i] = excl;
        carry += __shfl(x, 63);
    }
    if (lane == 0) rowptr[N_NODES] = carry;  // == E_TOT
}

__global__ void scan_write(const int* __restrict__ deg, const int* __restrict__ bofs,
                           int* __restrict__ rowptr, int* __restrict__ cursor) {
    __shared__ int a[256], b[256];
    int t = threadIdx.x;
    int i = blockIdx.x * 256 + t;
    int v = (i < N_NODES) ? deg[i] : 0;
    a[t] = v;
    __syncthreads();
    int* src = a; int* dst = b;
    for (int d = 1; d < 256; d <<= 1) {
        dst[t] = src[t] + ((t >= d) ? src[t - d] : 0);
        __syncthreads();
        int* tmp = src; src = dst; dst = tmp;
    }
    int excl = src[t] - v + bofs[blockIdx.x];
    if (i < N_NODES) { rowptr[i] = excl; cursor[i] = excl; }
}

// dst-partitioned fill: block (p = blockIdx&7) only handles dst in
// [p*PSZ, (p+1)*PSZ) -> partition's srclist window stays in one XCD's L2.
__global__ void fill_csr_part(const int* __restrict__ ei, int* __restrict__ cursor,
                              int* __restrict__ srclist) {
    int p = blockIdx.x & 7;
    int b = blockIdx.x >> 3;
    int lo = p * PSZ, hi = lo + PSZ;
    int e0 = (b * 256 + threadIdx.x) * 4;
    if (e0 >= E_TOT) return;
    bool self = e0 >= E_IN;
    int4 d4;
    if (!self) d4 = *(const int4*)&ei[E_IN + e0];
    else { int bb = e0 - E_IN; d4 = make_int4(bb, bb + 1, bb + 2, bb + 3); }
    int dd[4] = {d4.x, d4.y, d4.z, d4.w};
    #pragma unroll
    for (int q = 0; q < 4; ++q) {
        int d = dd[q];
        if (d >= lo && d < hi) {
            int s = self ? (e0 - E_IN + q) : ei[e0 + q];
            int pos = atomicAdd(&cursor[d], 1);
            srclist[pos] = s;
        }
    }
}

// ---------------- prep: x -> bf16, W -> W^T bf16 ----------------

__global__ void convert_x(const float* __restrict__ x, bfu* __restrict__ xb) {
    int i = (blockIdx.x * 256 + threadIdx.x) * 4;
    if (i >= N_NODES * 128) return;
    float4 v = *(const float4*)&x[i];
    ushort4 o;
    o.x = f2bf(v.x); o.y = f2bf(v.y); o.z = f2bf(v.z); o.w = f2bf(v.w);
    *(ushort4*)&xb[i] = o;
}

__global__ void transpose_w(const float* __restrict__ W1, const float* __restrict__ W2,
                            const float* __restrict__ W3,
                            bfu* __restrict__ Wt1, bfu* __restrict__ Wt2,
                            bfu* __restrict__ Wt3) {
    int idx = blockIdx.x * 256 + threadIdx.x;
    if (idx < 16384) {
        int k = idx >> 7, n = idx & 127;
        Wt1[n * 128 + k] = f2bf(W1[idx]);
    } else if (idx < 32768) {
        int r = idx - 16384;
        int k = r >> 7, n = r & 127;
        Wt2[n * 128 + k] = f2bf(W2[r]);
    } else if (idx < 32768 + 4096) {
        int r = idx - 32768;
        int k = r >> 5, n = r & 31;
        Wt3[n * 128 + k] = f2bf(W3[r]);
    }
}

// ---------------- MFMA GEMM: Y[N,COUT](bf16) = X[N,128](bf16) @ W ----------

template<int COUT>
__global__ __launch_bounds__(256) void gemm_mfma(const bfu* __restrict__ Xg,
                                                 const bfu* __restrict__ Wt,
                                                 bfu* __restrict__ Y) {
    constexpr int NT = COUT / 16;
    int wid  = threadIdx.x >> 6;
    int lane = threadIdx.x & 63;
    int m = lane & 15, quad = lane >> 4;
    int rbase = (blockIdx.x * 4 + wid) * 16;
    if (rbase >= N_NODES) return;
    int rA = rbase + m; if (rA >= N_NODES) rA = N_NODES - 1;

    const bfu* Ap = Xg + (size_t)rA * 128 + quad * 8;
    bf16x8 a0 = *(const bf16x8*)(Ap);
    bf16x8 a1 = *(const bf16x8*)(Ap + 32);
    bf16x8 a2 = *(const bf16x8*)(Ap + 64);
    bf16x8 a3 = *(const bf16x8*)(Ap + 96);

    const bfu* Bp = Wt + (size_t)m * 128 + quad * 8;
    f32x4 acc[NT];
    #pragma unroll
    for (int nt = 0; nt < NT; nt++) {
        const bfu* Bn = Bp + nt * 16 * 128;
        f32x4 c = {0.f, 0.f, 0.f, 0.f};
        c = __builtin_amdgcn_mfma_f32_16x16x32_bf16(a0, *(const bf16x8*)(Bn),      c, 0, 0, 0);
        c = __builtin_amdgcn_mfma_f32_16x16x32_bf16(a1, *(const bf16x8*)(Bn + 32), c, 0, 0, 0);
        c = __builtin_amdgcn_mfma_f32_16x16x32_bf16(a2, *(const bf16x8*)(Bn + 64), c, 0, 0, 0);
        c = __builtin_amdgcn_mfma_f32_16x16x32_bf16(a3, *(const bf16x8*)(Bn + 96), c, 0, 0, 0);
        acc[nt] = c;
    }
    #pragma unroll
    for (int nt = 0; nt < NT; nt++) {
        #pragma unroll
        for (int r = 0; r < 4; r++) {
            int row = rbase + quad * 4 + r;
            if (row < N_NODES)
                Y[(size_t)row * COUT + nt * 16 + m] = f2bf(acc[nt][r]);
        }
    }
}

// ---------------- per-node logit parts (bf16 h) ----------------

template<int H, int HID>
__global__ void logits_k(const bfu* __restrict__ Hb, const float* __restrict__ a_src,
                         const float* __restrict__ a_dst,
                         float* __restrict__ als, float* __restrict__ ald) {
    int id = blockIdx.x * 256 + threadIdx.x;
    if (id >= N_NODES * H) return;
    int n = id / H, h = id % H;
    const bfu* row = &Hb[(size_t)(n * H + h) * HID];
    float s = 0.f, dd = 0.f;
    #pragma unroll
    for (int j = 0; j < HID; j += 2) {
        unsigned u = *(const unsigned*)&row[j];
        float f0 = bf2f((bfu)(u & 0xffff)), f1 = bf2f((bfu)(u >> 16));
        s  += f0 * a_src[h * HID + j] + f1 * a_src[h * HID + j + 1];
        dd += f0 * a_dst[h * HID + j] + f1 * a_dst[h * HID + j + 1];
    }
    als[id] = s; ald[id] = dd;
}

// ---------------- aggregation ----------------

__global__ __launch_bounds__(256) void agg128(const bfu* __restrict__ Hb,
        const float* __restrict__ als, const float* __restrict__ ald,
        const int* __restrict__ rowptr, const int* __restrict__ srclist,
        const float* __restrict__ bias, bfu* __restrict__ out) {
    int wave = (blockIdx.x * 256 + threadIdx.x) >> 6;
    int lane = threadIdx.x & 63;
    if (wave >= N_NODES) return;
    int d = wave;
    int c0 = lane * 2;
    int h = lane >> 3;
    float ad = ald[d * 8 + h];
    float accx = 0.f, accy = 0.f, den = 0.f;
    int beg = rowptr[d], end = rowptr[d + 1];
    int j = beg;
    for (; j + 8 <= end; j += 8) {
        int s0 = srclist[j+0], s1 = srclist[j+1], s2 = srclist[j+2], s3 = srclist[j+3];
        int s4 = srclist[j+4], s5 = srclist[j+5], s6 = srclist[j+6], s7 = srclist[j+7];
        unsigned u0 = *(const unsigned*)&Hb[(size_t)s0 * 128 + c0];
        unsigned u1 = *(const unsigned*)&Hb[(size_t)s1 * 128 + c0];
        unsigned u2 = *(const unsigned*)&Hb[(size_t)s2 * 128 + c0];
        unsigned u3 = *(const unsigned*)&Hb[(size_t)s3 * 128 + c0];
        unsigned u4 = *(const unsigned*)&Hb[(size_t)s4 * 128 + c0];
        unsigned u5 = *(const unsigned*)&Hb[(size_t)s5 * 128 + c0];
        unsigned u6 = *(const unsigned*)&Hb[(size_t)s6 * 128 + c0];
        unsigned u7 = *(const unsigned*)&Hb[(size_t)s7 * 128 + c0];
        float x0 = als[s0*8+h], x1 = als[s1*8+h], x2 = als[s2*8+h], x3 = als[s3*8+h];
        float x4 = als[s4*8+h], x5 = als[s5*8+h], x6 = als[s6*8+h], x7 = als[s7*8+h];
        float l, w;
        l = x0 + ad; l = fmaxf(l, NEG*l); w = __expf(l); den += w;
        accx = fmaf(w, bf2f((bfu)(u0 & 0xffff)), accx); accy = fmaf(w, bf2f((bfu)(u0 >> 16)), accy);
        l = x1 + ad; l = fmaxf(l, NEG*l); w = __expf(l); den += w;
        accx = fmaf(w, bf2f((bfu)(u1 & 0xffff)), accx); accy = fmaf(w, bf2f((bfu)(u1 >> 16)), accy);
        l = x2 + ad; l = fmaxf(l, NEG*l); w = __expf(l); den += w;
        accx = fmaf(w, bf2f((bfu)(u2 & 0xffff)), accx); accy = fmaf(w, bf2f((bfu)(u2 >> 16)), accy);
        l = x3 + ad; l = fmaxf(l, NEG*l); w = __expf(l); den += w;
        accx = fmaf(w, bf2f((bfu)(u3 & 0xffff)), accx); accy = fmaf(w, bf2f((bfu)(u3 >> 16)), accy);
        l = x4 + ad; l = fmaxf(l, NEG*l); w = __expf(l); den += w;
        accx = fmaf(w, bf2f((bfu)(u4 & 0xffff)), accx); accy = fmaf(w, bf2f((bfu)(u4 >> 16)), accy);
        l = x5 + ad; l = fmaxf(l, NEG*l); w = __expf(l); den += w;
        accx = fmaf(w, bf2f((bfu)(u5 & 0xffff)), accx); accy = fmaf(w, bf2f((bfu)(u5 >> 16)), accy);
        l = x6 + ad; l = fmaxf(l, NEG*l); w = __expf(l); den += w;
        accx = fmaf(w, bf2f((bfu)(u6 & 0xffff)), accx); accy = fmaf(w, bf2f((bfu)(u6 >> 16)), accy);
        l = x7 + ad; l = fmaxf(l, NEG*l); w = __expf(l); den += w;
        accx = fmaf(w, bf2f((bfu)(u7 & 0xffff)), accx); accy = fmaf(w, bf2f((bfu)(u7 >> 16)), accy);
    }
    for (; j < end; ++j) {
        int s = srclist[j];
        unsigned u = *(const unsigned*)&Hb[(size_t)s * 128 + c0];
        float l = als[s*8+h] + ad; l = fmaxf(l, NEG*l);
        float w = __expf(l); den += w;
        accx = fmaf(w, bf2f((bfu)(u & 0xffff)), accx);
        accy = fmaf(w, bf2f((bfu)(u >> 16)), accy);
    }
    float rden = 1.f / den;
    float ox = accx * rden + bias[c0];     ox = ox > 0.f ? ox : 0.f;
    float oy = accy * rden + bias[c0 + 1]; oy = oy > 0.f ? oy : 0.f;
    ushort2 o; o.x = f2bf(ox); o.y = f2bf(oy);
    *(ushort2*)&out[(size_t)d * 128 + c0] = o;
}

__global__ __launch_bounds__(256) void agg32(const bfu* __restrict__ Hb,
        const float* __restrict__ als, const float* __restrict__ ald,
        const int* __restrict__ rowptr, const int* __restrict__ srclist,
        const float* __restrict__ bias, float* __restrict__ out) {
    int wave = (blockIdx.x * 256 + threadIdx.x) >> 6;
    int lane = threadIdx.x & 63;
    int d = wave * 4 + (lane >> 4);
    int c0 = (lane & 15) * 2;
    if (d >= N_NODES) return;
    float adv = ald[d];
    float accx = 0.f, accy = 0.f, den = 0.f;
    int beg = rowptr[d], end = rowptr[d + 1];
    int j = beg;
    for (; j + 4 <= end; j += 4) {
        int s0 = srclist[j+0], s1 = srclist[j+1], s2 = srclist[j+2], s3 = srclist[j+3];
        unsigned u0 = *(const unsigned*)&Hb[(size_t)s0 * 32 + c0];
        unsigned u1 = *(const unsigned*)&Hb[(size_t)s1 * 32 + c0];
        unsigned u2 = *(const unsigned*)&Hb[(size_t)s2 * 32 + c0];
        unsigned u3 = *(const unsigned*)&Hb[(size_t)s3 * 32 + c0];
        float x0 = als[s0], x1 = als[s1], x2 = als[s2], x3 = als[s3];
        float l, w;
        l = x0 + adv; l = fmaxf(l, NEG*l); w = __expf(l); den += w;
        accx = fmaf(w, bf2f((bfu)(u0 & 0xffff)), accx); accy = fmaf(w, bf2f((bfu)(u0 >> 16)), accy);
        l = x1 + adv; l = fmaxf(l, NEG*l); w = __expf(l); den += w;
        accx = fmaf(w, bf2f((bfu)(u1 & 0xffff)), accx); accy = fmaf(w, bf2f((bfu)(u1 >> 16)), accy);
        l = x2 + adv; l = fmaxf(l, NEG*l); w = __expf(l); den += w;
        accx = fmaf(w, bf2f((bfu)(u2 & 0xffff)), accx); accy = fmaf(w, bf2f((bfu)(u2 >> 16)), accy);
        l = x3 + adv; l = fmaxf(l, NEG*l); w = __expf(l); den += w;
        accx = fmaf(w, bf2f((bfu)(u3 & 0xffff)), accx); accy = fmaf(w, bf2f((bfu)(u3 >> 16)), accy);
    }
    for (; j < end; ++j) {
        int s = srclist[j];
        unsigned u = *(const unsigned*)&Hb[(size_t)s * 32 + c0];
        float l = als[s] + adv; l = fmaxf(l, NEG*l);
        float w = __expf(l); den += w;
        accx = fmaf(w, bf2f((bfu)(u & 0xffff)), accx);
        accy = fmaf(w, bf2f((bfu)(u >> 16)), accy);
    }
    float rden = 1.f / den;
    float ox = accx * rden + bias[c0];
    float oy = accy * rden + bias[c0 + 1];
    *(float2*)&out[(size_t)d * 32 + c0] = make_float2(ox, oy);
}

// ---------------- global mean pool ----------------
__global__ void pool32(const float* __restrict__ h3, float* __restrict__ outp) {
    __shared__ float lds[256];
    int t = threadIdx.x;
    int c = t & 31, g = t >> 5;
    float acc = 0.f;
    for (int n = blockIdx.x * 8 + g; n < N_NODES; n += gridDim.x * 8)
        acc += h3[n * 32 + c];
    lds[t] = acc;
    __syncthreads();
    if (g == 0) {
        float s = 0.f;
        for (int gg = 0; gg < 8; ++gg) s += lds[gg * 32 + c];
        atomicAdd(&outp[c], s * (1.0f / N_NODES));
    }
}

// ---------------- launch ----------------

extern "C" void kernel_launch(void* const* d_in, const int* in_sizes, int n_in,
                              void* d_out, int out_size, void* d_ws, size_t ws_size,
                              hipStream_t stream) {
    (void)in_sizes; (void)n_in; (void)out_size; (void)ws_size;
    const float* x   = (const float*)d_in[0];
    const int*   ei  = (const int*)d_in[1];
    const float* W1  = (const float*)d_in[2];
    const float* as1 = (const float*)d_in[3];
    const float* ad1 = (const float*)d_in[4];
    const float* b1  = (const float*)d_in[5];
    const float* W2  = (const float*)d_in[6];
    const float* as2 = (const float*)d_in[7];
    const float* ad2 = (const float*)d_in[8];
    const float* b2  = (const float*)d_in[9];
    const float* W3  = (const float*)d_in[10];
    const float* as3 = (const float*)d_in[11];
    const float* ad3 = (const float*)d_in[12];
    const float* b3  = (const float*)d_in[13];

    char* ws = (char*)d_ws;
    size_t off = 0;
    auto carve = [&](size_t bytes) { void* p = ws + off; off += (bytes + 255) & ~size_t(255); return p; };
    bfu*   bufX    = (bfu*)carve(size_t(N_NODES) * 128 * 2);
    bfu*   bufH    = (bfu*)carve(size_t(N_NODES) * 128 * 2);
    bfu*   bufF    = (bfu*)carve(size_t(N_NODES) * 128 * 2);
    float* out3    = (float*)carve(size_t(N_NODES) * 32 * 4);
    float* als     = (float*)carve(size_t(N_NODES) * 8 * 4);
    float* ald     = (float*)carve(size_t(N_NODES) * 8 * 4);
    int*   deg     = (int*)carve(size_t(N_NODES) * 4);
    int*   rowptr  = (int*)carve(size_t(N_NODES + 1) * 4);
    int*   cursor  = (int*)carve(size_t(N_NODES) * 4);
    int*   bsum    = (int*)carve(512 * 4);
    int*   bofs    = (int*)carve(512 * 4);
    bfu*   Wt1     = (bfu*)carve(128 * 128 * 2);
    bfu*   Wt2     = (bfu*)carve(128 * 128 * 2);
    bfu*   Wt3     = (bfu*)carve(32 * 128 * 2);
    int*   srclist = (int*)carve(size_t(E_TOT) * 4);

    const int SCAN_B  = (N_NODES + 255) / 256;
    const int EDGE_B4 = (E_TOT / 4 + 255) / 256;   // 1661
    const int GEMM_B  = (N_NODES + 63) / 64;

    hipMemsetAsync(deg, 0, size_t(N_NODES) * 4, stream);
    hipMemsetAsync(d_out, 0, 32 * 4, stream);

    // prep
    convert_x  <<<(N_NODES * 128 / 4 + 255) / 256, 256, 0, stream>>>(x, bufX);
    transpose_w<<<(36864 + 255) / 256, 256, 0, stream>>>(W1, W2, W3, Wt1, Wt2, Wt3);

    // CSR build (graph shared by all 3 layers)
    count_deg  <<<EDGE_B4, 256, 0, stream>>>(ei, deg);
    scan_partial<<<SCAN_B, 256, 0, stream>>>(deg, bsum);
    scan_bsums <<<1, 64, 0, stream>>>(bsum, bofs, rowptr, SCAN_B);
    scan_write <<<SCAN_B, 256, 0, stream>>>(deg, bofs, rowptr, cursor);
    fill_csr_part<<<EDGE_B4 * P_XCD, 256, 0, stream>>>(ei, cursor, srclist);

    // layer 1
    gemm_mfma<128><<<GEMM_B, 256, 0, stream>>>(bufX, Wt1, bufH);
    logits_k<8, 16><<<(N_NODES * 8 + 255) / 256, 256, 0, stream>>>(bufH, as1, ad1, als, ald);
    agg128<<<(N_NODES + 3) / 4, 256, 0, stream>>>(bufH, als, ald, rowptr, srclist, b1, bufF);

    // layer 2
    gemm_mfma<128><<<GEMM_B, 256, 0, stream>>>(bufF, Wt2, bufH);
    logits_k<8, 16><<<(N_NODES * 8 + 255) / 256, 256, 0, stream>>>(bufH, as2, ad2, als, ald);
    agg128<<<(N_NODES + 3) / 4, 256, 0, stream>>>(bufH, als, ald, rowptr, srclist, b2, bufF);

    // layer 3
    gemm_mfma<32><<<GEMM_B, 256, 0, stream>>>(bufF, Wt3, bufH);
    logits_k<1, 32><<<(N_NODES + 255) / 256, 256, 0, stream>>>(bufH, as3, ad3, als, ald);
    agg32<<<(N_NODES / 4 + 3) / 4, 256, 0, stream>>>(bufH, als, ald, rowptr, srclist, b3, out3);
    pool32<<<64, 256, 0, stream>>>(out3, (float*)d_out);
}

// Round 6
// 612.745 us; speedup vs baseline: 1.3966x; 1.0250x over previous
//
#include <hip/hip_runtime.h>

// GAT (3-layer) on MI355X.
// R5: agg kernels pack multiple dst nodes per wave (agg128: 4 dst x 16 lanes
// x 8ch; agg32: 8 dst x 8 lanes x 4ch). R4 showed agg128 VALU-issue-bound
// (VALUBusy 64%, hbm 41%): one edge per wave-instruction. Now 4 (8) edges
// share each wave-instruction -> ~2.3x less VALU/edge; row gathers become
// 16B/lane (1KB per instr). Unroll x2 keeps 8 gathers in flight per wave.

typedef unsigned short bfu;
typedef __attribute__((ext_vector_type(8))) short bf16x8;
typedef __attribute__((ext_vector_type(4))) float f32x4;

constexpr int N_NODES = 100000;
constexpr int E_IN    = 1600000;
constexpr int E_TOT   = E_IN + N_NODES;   // + self loops
constexpr float NEG   = 0.2f;
constexpr int P_XCD   = 8;
constexpr int PSZ     = N_NODES / P_XCD;  // 12500

__device__ inline float bf2f(bfu u) {
    union { unsigned i; float f; } c; c.i = ((unsigned)u) << 16; return c.f;
}
__device__ inline bfu f2bf(float f) {
    union { float f; unsigned i; } c; c.f = f;
    unsigned x = c.i;
    return (bfu)((x + 0x7fffu + ((x >> 16) & 1u)) >> 16);
}
// bf16 pair unpack: low element = bits<<16, high element = bits&0xffff0000
__device__ inline float blo(unsigned u) {
    union { unsigned i; float f; } c; c.i = u << 16; return c.f;
}
__device__ inline float bhi(unsigned u) {
    union { unsigned i; float f; } c; c.i = u & 0xffff0000u; return c.f;
}

// ---------------- CSR build ----------------

__global__ void count_deg(const int* __restrict__ ei, int* __restrict__ deg) {
    int e0 = (blockIdx.x * 256 + threadIdx.x) * 4;
    if (e0 >= E_TOT) return;
    int4 d4;
    if (e0 < E_IN) d4 = *(const int4*)&ei[E_IN + e0];
    else { int b = e0 - E_IN; d4 = make_int4(b, b + 1, b + 2, b + 3); }
    atomicAdd(&deg[d4.x], 1);
    atomicAdd(&deg[d4.y], 1);
    atomicAdd(&deg[d4.z], 1);
    atomicAdd(&deg[d4.w], 1);
}

__global__ void scan_partial(const int* __restrict__ deg, int* __restrict__ bsum) {
    __shared__ int lds[256];
    int i = blockIdx.x * 256 + threadIdx.x;
    int v = (i < N_NODES) ? deg[i] : 0;
    lds[threadIdx.x] = v;
    __syncthreads();
    for (int s = 128; s > 0; s >>= 1) {
        if (threadIdx.x < s) lds[threadIdx.x] += lds[threadIdx.x + s];
        __syncthreads();
    }
    if (threadIdx.x == 0) bsum[blockIdx.x] = lds[0];
}

__global__ void scan_bsums(const int* __restrict__ bsum, int* __restrict__ bofs,
                           int* __restrict__ rowptr, int nb) {
    int lane = threadIdx.x;  // 64 threads
    int carry = 0;
    for (int base = 0; base < nb; base += 64) {
        int i = base + lane;
        int v = (i < nb) ? bsum[i] : 0;
        int x = v;
        #pragma unroll
        for (int d = 1; d < 64; d <<= 1) {
            int y = __shfl_up(x, d);
            if (lane >= d) x += y;
        }
        int excl = x - v + carry;
        if (i < nb) bofs[i] = excl;
        carry += __shfl(x, 63);
    }
    if (lane == 0) rowptr[N_NODES] = carry;  // == E_TOT
}

__global__ void scan_write(const int* __restrict__ deg, const int* __restrict__ bofs,
                           int* __restrict__ rowptr, int* __restrict__ cursor) {
    __shared__ int a[256], b[256];
    int t = threadIdx.x;
    int i = blockIdx.x * 256 + t;
    int v = (i < N_NODES) ? deg[i] : 0;
    a[t] = v;
    __syncthreads();
    int* src = a; int* dst = b;
    for (int d = 1; d < 256; d <<= 1) {
        dst[t] = src[t] + ((t >= d) ? src[t - d] : 0);
        __syncthreads();
        int* tmp = src; src = dst; dst = tmp;
    }
    int excl = src[t] - v + bofs[blockIdx.x];
    if (i < N_NODES) { rowptr[i] = excl; cursor[i] = excl; }
}

// dst-partitioned fill: block (p = blockIdx&7) only handles dst in
// [p*PSZ, (p+1)*PSZ) -> partition's srclist window stays in one XCD's L2.
__global__ void fill_csr_part(const int* __restrict__ ei, int* __restrict__ cursor,
                              int* __restrict__ srclist) {
    int p = blockIdx.x & 7;
    int b = blockIdx.x >> 3;
    int lo = p * PSZ, hi = lo + PSZ;
    int e0 = (b * 256 + threadIdx.x) * 4;
    if (e0 >= E_TOT) return;
    bool self = e0 >= E_IN;
    int4 d4;
    if (!self) d4 = *(const int4*)&ei[E_IN + e0];
    else { int bb = e0 - E_IN; d4 = make_int4(bb, bb + 1, bb + 2, bb + 3); }
    int dd[4] = {d4.x, d4.y, d4.z, d4.w};
    #pragma unroll
    for (int q = 0; q < 4; ++q) {
        int d = dd[q];
        if (d >= lo && d < hi) {
            int s = self ? (e0 - E_IN + q) : ei[e0 + q];
            int pos = atomicAdd(&cursor[d], 1);
            srclist[pos] = s;
        }
    }
}

// ---------------- prep: x -> bf16, W -> W^T bf16 ----------------

__global__ void convert_x(const float* __restrict__ x, bfu* __restrict__ xb) {
    int i = (blockIdx.x * 256 + threadIdx.x) * 4;
    if (i >= N_NODES * 128) return;
    float4 v = *(const float4*)&x[i];
    ushort4 o;
    o.x = f2bf(v.x); o.y = f2bf(v.y); o.z = f2bf(v.z); o.w = f2bf(v.w);
    *(ushort4*)&xb[i] = o;
}

__global__ void transpose_w(const float* __restrict__ W1, const float* __restrict__ W2,
                            const float* __restrict__ W3,
                            bfu* __restrict__ Wt1, bfu* __restrict__ Wt2,
                            bfu* __restrict__ Wt3) {
    int idx = blockIdx.x * 256 + threadIdx.x;
    if (idx < 16384) {
        int k = idx >> 7, n = idx & 127;
        Wt1[n * 128 + k] = f2bf(W1[idx]);
    } else if (idx < 32768) {
        int r = idx - 16384;
        int k = r >> 7, n = r & 127;
        Wt2[n * 128 + k] = f2bf(W2[r]);
    } else if (idx < 32768 + 4096) {
        int r = idx - 32768;
        int k = r >> 5, n = r & 31;
        Wt3[n * 128 + k] = f2bf(W3[r]);
    }
}

// ---------------- MFMA GEMM: Y[N,COUT](bf16) = X[N,128](bf16) @ W ----------

template<int COUT>
__global__ __launch_bounds__(256) void gemm_mfma(const bfu* __restrict__ Xg,
                                                 const bfu* __restrict__ Wt,
                                                 bfu* __restrict__ Y) {
    constexpr int NT = COUT / 16;
    int wid  = threadIdx.x >> 6;
    int lane = threadIdx.x & 63;
    int m = lane & 15, quad = lane >> 4;
    int rbase = (blockIdx.x * 4 + wid) * 16;
    if (rbase >= N_NODES) return;
    int rA = rbase + m; if (rA >= N_NODES) rA = N_NODES - 1;

    const bfu* Ap = Xg + (size_t)rA * 128 + quad * 8;
    bf16x8 a0 = *(const bf16x8*)(Ap);
    bf16x8 a1 = *(const bf16x8*)(Ap + 32);
    bf16x8 a2 = *(const bf16x8*)(Ap + 64);
    bf16x8 a3 = *(const bf16x8*)(Ap + 96);

    const bfu* Bp = Wt + (size_t)m * 128 + quad * 8;
    f32x4 acc[NT];
    #pragma unroll
    for (int nt = 0; nt < NT; nt++) {
        const bfu* Bn = Bp + nt * 16 * 128;
        f32x4 c = {0.f, 0.f, 0.f, 0.f};
        c = __builtin_amdgcn_mfma_f32_16x16x32_bf16(a0, *(const bf16x8*)(Bn),      c, 0, 0, 0);
        c = __builtin_amdgcn_mfma_f32_16x16x32_bf16(a1, *(const bf16x8*)(Bn + 32), c, 0, 0, 0);
        c = __builtin_amdgcn_mfma_f32_16x16x32_bf16(a2, *(const bf16x8*)(Bn + 64), c, 0, 0, 0);
        c = __builtin_amdgcn_mfma_f32_16x16x32_bf16(a3, *(const bf16x8*)(Bn + 96), c, 0, 0, 0);
        acc[nt] = c;
    }
    #pragma unroll
    for (int nt = 0; nt < NT; nt++) {
        #pragma unroll
        for (int r = 0; r < 4; r++) {
            int row = rbase + quad * 4 + r;
            if (row < N_NODES)
                Y[(size_t)row * COUT + nt * 16 + m] = f2bf(acc[nt][r]);
        }
    }
}

// ---------------- per-node logit parts (bf16 h) ----------------

template<int H, int HID>
__global__ void logits_k(const bfu* __restrict__ Hb, const float* __restrict__ a_src,
                         const float* __restrict__ a_dst,
                         float* __restrict__ als, float* __restrict__ ald) {
    int id = blockIdx.x * 256 + threadIdx.x;
    if (id >= N_NODES * H) return;
    int n = id / H, h = id % H;
    const bfu* row = &Hb[(size_t)(n * H + h) * HID];
    float s = 0.f, dd = 0.f;
    #pragma unroll
    for (int j = 0; j < HID; j += 2) {
        unsigned u = *(const unsigned*)&row[j];
        float f0 = blo(u), f1 = bhi(u);
        s  += f0 * a_src[h * HID + j] + f1 * a_src[h * HID + j + 1];
        dd += f0 * a_dst[h * HID + j] + f1 * a_dst[h * HID + j + 1];
    }
    als[id] = s; ald[id] = dd;
}

// ---------------- aggregation ----------------
// agg128: 4 dst per wave; 16 lanes per dst; lane owns 8 channels (16B load).
// head h = (lane&15)>>1. Per-edge weight computed once per sub-group; each
// wave-instruction serves up to 4 edges. Unroll x2 -> 8 gathers in flight.

__global__ __launch_bounds__(256) void agg128(const bfu* __restrict__ Hb,
        const float* __restrict__ als, const float* __restrict__ ald,
        const int* __restrict__ rowptr, const int* __restrict__ srclist,
        const float* __restrict__ bias, bfu* __restrict__ out) {
    int wave = (blockIdx.x * 256 + threadIdx.x) >> 6;
    int lane = threadIdx.x & 63;
    int sub  = lane >> 4;          // which of 4 dst
    int li   = lane & 15;
    int d    = wave * 4 + sub;
    if (d >= N_NODES) return;
    int c0 = li * 8;               // 8 channels per lane
    int h  = li >> 1;              // 8 heads over 16 lanes
    float ad = ald[d * 8 + h];
    float a0=0.f,a1=0.f,a2=0.f,a3=0.f,a4=0.f,a5=0.f,a6=0.f,a7=0.f,den=0.f;
    int j = rowptr[d], end = rowptr[d + 1];
    for (; j + 2 <= end; j += 2) {
        int s0 = srclist[j], s1 = srclist[j + 1];
        uint4 u0 = *(const uint4*)(Hb + (size_t)s0 * 128 + c0);
        uint4 u1 = *(const uint4*)(Hb + (size_t)s1 * 128 + c0);
        float x0 = als[s0 * 8 + h], x1 = als[s1 * 8 + h];
        float l0 = x0 + ad; l0 = fmaxf(l0, NEG * l0); float w0 = __expf(l0);
        float l1 = x1 + ad; l1 = fmaxf(l1, NEG * l1); float w1 = __expf(l1);
        den += w0 + w1;
        a0 = fmaf(w0, blo(u0.x), a0); a1 = fmaf(w0, bhi(u0.x), a1);
        a2 = fmaf(w0, blo(u0.y), a2); a3 = fmaf(w0, bhi(u0.y), a3);
        a4 = fmaf(w0, blo(u0.z), a4); a5 = fmaf(w0, bhi(u0.z), a5);
        a6 = fmaf(w0, blo(u0.w), a6); a7 = fmaf(w0, bhi(u0.w), a7);
        a0 = fmaf(w1, blo(u1.x), a0); a1 = fmaf(w1, bhi(u1.x), a1);
        a2 = fmaf(w1, blo(u1.y), a2); a3 = fmaf(w1, bhi(u1.y), a3);
        a4 = fmaf(w1, blo(u1.z), a4); a5 = fmaf(w1, bhi(u1.z), a5);
        a6 = fmaf(w1, blo(u1.w), a6); a7 = fmaf(w1, bhi(u1.w), a7);
    }
    if (j < end) {
        int s0 = srclist[j];
        uint4 u0 = *(const uint4*)(Hb + (size_t)s0 * 128 + c0);
        float x0 = als[s0 * 8 + h];
        float l0 = x0 + ad; l0 = fmaxf(l0, NEG * l0); float w0 = __expf(l0);
        den += w0;
        a0 = fmaf(w0, blo(u0.x), a0); a1 = fmaf(w0, bhi(u0.x), a1);
        a2 = fmaf(w0, blo(u0.y), a2); a3 = fmaf(w0, bhi(u0.y), a3);
        a4 = fmaf(w0, blo(u0.z), a4); a5 = fmaf(w0, bhi(u0.z), a5);
        a6 = fmaf(w0, blo(u0.w), a6); a7 = fmaf(w0, bhi(u0.w), a7);
    }
    float r = 1.f / den;
    float4 b0 = *(const float4*)&bias[c0];
    float4 b1 = *(const float4*)&bias[c0 + 4];
    float o0 = fmaxf(fmaf(a0, r, b0.x), 0.f);
    float o1 = fmaxf(fmaf(a1, r, b0.y), 0.f);
    float o2 = fmaf(a2, r, b0.z); o2 = fmaxf(o2, 0.f);
    float o3 = fmaxf(fmaf(a3, r, b0.w), 0.f);
    float o4 = fmaxf(fmaf(a4, r, b1.x), 0.f);
    float o5 = fmaxf(fmaf(a5, r, b1.y), 0.f);
    float o6 = fmaxf(fmaf(a6, r, b1.z), 0.f);
    float o7 = fmaxf(fmaf(a7, r, b1.w), 0.f);
    uint4 st;
    st.x = (unsigned)f2bf(o0) | ((unsigned)f2bf(o1) << 16);
    st.y = (unsigned)f2bf(o2) | ((unsigned)f2bf(o3) << 16);
    st.z = (unsigned)f2bf(o4) | ((unsigned)f2bf(o5) << 16);
    st.w = (unsigned)f2bf(o6) | ((unsigned)f2bf(o7) << 16);
    *(uint4*)&out[(size_t)d * 128 + c0] = st;
}

// agg32: 8 dst per wave; 8 lanes per dst; lane owns 4 channels (8B load).
// H=1, no relu, fp32 out.
__global__ __launch_bounds__(256) void agg32(const bfu* __restrict__ Hb,
        const float* __restrict__ als, const float* __restrict__ ald,
        const int* __restrict__ rowptr, const int* __restrict__ srclist,
        const float* __restrict__ bias, float* __restrict__ out) {
    int wave = (blockIdx.x * 256 + threadIdx.x) >> 6;
    int lane = threadIdx.x & 63;
    int sub  = lane >> 3;          // which of 8 dst
    int li   = lane & 7;
    int d    = wave * 8 + sub;
    if (d >= N_NODES) return;
    int c0 = li * 4;
    float adv = ald[d];
    float a0=0.f,a1=0.f,a2=0.f,a3=0.f,den=0.f;
    int j = rowptr[d], end = rowptr[d + 1];
    for (; j + 2 <= end; j += 2) {
        int s0 = srclist[j], s1 = srclist[j + 1];
        uint2 u0 = *(const uint2*)(Hb + (size_t)s0 * 32 + c0);
        uint2 u1 = *(const uint2*)(Hb + (size_t)s1 * 32 + c0);
        float x0 = als[s0], x1 = als[s1];
        float l0 = x0 + adv; l0 = fmaxf(l0, NEG * l0); float w0 = __expf(l0);
        float l1 = x1 + adv; l1 = fmaxf(l1, NEG * l1); float w1 = __expf(l1);
        den += w0 + w1;
        a0 = fmaf(w0, blo(u0.x), a0); a1 = fmaf(w0, bhi(u0.x), a1);
        a2 = fmaf(w0, blo(u0.y), a2); a3 = fmaf(w0, bhi(u0.y), a3);
        a0 = fmaf(w1, blo(u1.x), a0); a1 = fmaf(w1, bhi(u1.x), a1);
        a2 = fmaf(w1, blo(u1.y), a2); a3 = fmaf(w1, bhi(u1.y), a3);
    }
    if (j < end) {
        int s0 = srclist[j];
        uint2 u0 = *(const uint2*)(Hb + (size_t)s0 * 32 + c0);
        float x0 = als[s0];
        float l0 = x0 + adv; l0 = fmaxf(l0, NEG * l0); float w0 = __expf(l0);
        den += w0;
        a0 = fmaf(w0, blo(u0.x), a0); a1 = fmaf(w0, bhi(u0.x), a1);
        a2 = fmaf(w0, blo(u0.y), a2); a3 = fmaf(w0, bhi(u0.y), a3);
    }
    float r = 1.f / den;
    float4 bv = *(const float4*)&bias[c0];
    float4 o;
    o.x = fmaf(a0, r, bv.x); o.y = fmaf(a1, r, bv.y);
    o.z = fmaf(a2, r, bv.z); o.w = fmaf(a3, r, bv.w);
    *(float4*)&out[(size_t)d * 32 + c0] = o;
}

// ---------------- global mean pool ----------------
__global__ void pool32(const float* __restrict__ h3, float* __restrict__ outp) {
    __shared__ float lds[256];
    int t = threadIdx.x;
    int c = t & 31, g = t >> 5;
    float acc = 0.f;
    for (int n = blockIdx.x * 8 + g; n < N_NODES; n += gridDim.x * 8)
        acc += h3[n * 32 + c];
    lds[t] = acc;
    __syncthreads();
    if (g == 0) {
        float s = 0.f;
        for (int gg = 0; gg < 8; ++gg) s += lds[gg * 32 + c];
        atomicAdd(&outp[c], s * (1.0f / N_NODES));
    }
}

// ---------------- launch ----------------

extern "C" void kernel_launch(void* const* d_in, const int* in_sizes, int n_in,
                              void* d_out, int out_size, void* d_ws, size_t ws_size,
                              hipStream_t stream) {
    (void)in_sizes; (void)n_in; (void)out_size; (void)ws_size;
    const float* x   = (const float*)d_in[0];
    const int*   ei  = (const int*)d_in[1];
    const float* W1  = (const float*)d_in[2];
    const float* as1 = (const float*)d_in[3];
    const float* ad1 = (const float*)d_in[4];
    const float* b1  = (const float*)d_in[5];
    const float* W2  = (const float*)d_in[6];
    const float* as2 = (const float*)d_in[7];
    const float* ad2 = (const float*)d_in[8];
    const float* b2  = (const float*)d_in[9];
    const float* W3  = (const float*)d_in[10];
    const float* as3 = (const float*)d_in[11];
    const float* ad3 = (const float*)d_in[12];
    const float* b3  = (const float*)d_in[13];

    char* ws = (char*)d_ws;
    size_t off = 0;
    auto carve = [&](size_t bytes) { void* p = ws + off; off += (bytes + 255) & ~size_t(255); return p; };
    bfu*   bufX    = (bfu*)carve(size_t(N_NODES) * 128 * 2);
    bfu*   bufH    = (bfu*)carve(size_t(N_NODES) * 128 * 2);
    bfu*   bufF    = (bfu*)carve(size_t(N_NODES) * 128 * 2);
    float* out3    = (float*)carve(size_t(N_NODES) * 32 * 4);
    float* als     = (float*)carve(size_t(N_NODES) * 8 * 4);
    float* ald     = (float*)carve(size_t(N_NODES) * 8 * 4);
    int*   deg     = (int*)carve(size_t(N_NODES) * 4);
    int*   rowptr  = (int*)carve(size_t(N_NODES + 1) * 4);
    int*   cursor  = (int*)carve(size_t(N_NODES) * 4);
    int*   bsum    = (int*)carve(512 * 4);
    int*   bofs    = (int*)carve(512 * 4);
    bfu*   Wt1     = (bfu*)carve(128 * 128 * 2);
    bfu*   Wt2     = (bfu*)carve(128 * 128 * 2);
    bfu*   Wt3     = (bfu*)carve(32 * 128 * 2);
    int*   srclist = (int*)carve(size_t(E_TOT) * 4);

    const int SCAN_B  = (N_NODES + 255) / 256;
    const int EDGE_B4 = (E_TOT / 4 + 255) / 256;   // 1661
    const int GEMM_B  = (N_NODES + 63) / 64;

    hipMemsetAsync(deg, 0, size_t(N_NODES) * 4, stream);
    hipMemsetAsync(d_out, 0, 32 * 4, stream);

    // prep
    convert_x  <<<(N_NODES * 128 / 4 + 255) / 256, 256, 0, stream>>>(x, bufX);
    transpose_w<<<(36864 + 255) / 256, 256, 0, stream>>>(W1, W2, W3, Wt1, Wt2, Wt3);

    // CSR build (graph shared by all 3 layers)
    count_deg  <<<EDGE_B4, 256, 0, stream>>>(ei, deg);
    scan_partial<<<SCAN_B, 256, 0, stream>>>(deg, bsum);
    scan_bsums <<<1, 64, 0, stream>>>(bsum, bofs, rowptr, SCAN_B);
    scan_write <<<SCAN_B, 256, 0, stream>>>(deg, bofs, rowptr, cursor);
    fill_csr_part<<<EDGE_B4 * P_XCD, 256, 0, stream>>>(ei, cursor, srclist);

    // layer 1
    gemm_mfma<128><<<GEMM_B, 256, 0, stream>>>(bufX, Wt1, bufH);
    logits_k<8, 16><<<(N_NODES * 8 + 255) / 256, 256, 0, stream>>>(bufH, as1, ad1, als, ald);
    agg128<<<(N_NODES + 15) / 16, 256, 0, stream>>>(bufH, als, ald, rowptr, srclist, b1, bufF);

    // layer 2
    gemm_mfma<128><<<GEMM_B, 256, 0, stream>>>(bufF, Wt2, bufH);
    logits_k<8, 16><<<(N_NODES * 8 + 255) / 256, 256, 0, stream>>>(bufH, as2, ad2, als, ald);
    agg128<<<(N_NODES + 15) / 16, 256, 0, stream>>>(bufH, als, ald, rowptr, srclist, b2, bufF);

    // layer 3
    gemm_mfma<32><<<GEMM_B, 256, 0, stream>>>(bufF, Wt3, bufH);
    logits_k<1, 32><<<(N_NODES + 255) / 256, 256, 0, stream>>>(bufH, as3, ad3, als, ald);
    agg32<<<(N_NODES + 31) / 32, 256, 0, stream>>>(bufH, als, ald, rowptr, srclist, b3, out3);
    pool32<<<64, 256, 0, stream>>>(out3, (float*)d_out);
}

// Round 7
// 526.257 us; speedup vs baseline: 1.6261x; 1.1643x over previous
//
#include <hip/hip_runtime.h>

// GAT (3-layer) on MI355X.
// R6: (a) bucket CSR: srclist[d*64+slot], one atomic/edge in partitioned fill
//     -> count_deg + 3 scan kernels eliminated (deg = cursor after fill);
//     (b) agg edge loops unrolled x4 (R5: MLP-bound, VALU 33%, hbm 45%,
//     VGPR only 20 -> double gathers in flight);
//     (c) layer-1 GEMM reads fp32 x directly (cvt in register) -> convert_x
//     pass and bufX eliminated.

typedef unsigned short bfu;
typedef __attribute__((ext_vector_type(8))) short bf16x8;
typedef __attribute__((ext_vector_type(4))) float f32x4;

constexpr int N_NODES = 100000;
constexpr int E_IN    = 1600000;
constexpr int E_TOT   = E_IN + N_NODES;   // + self loops
constexpr float NEG   = 0.2f;
constexpr int P_XCD   = 8;
constexpr int PSZ     = N_NODES / P_XCD;  // 12500
constexpr int CAP     = 64;               // srclist slots per node (Poisson(16)+1; P(overflow)~1e-20)

__device__ inline float bf2f(bfu u) {
    union { unsigned i; float f; } c; c.i = ((unsigned)u) << 16; return c.f;
}
__device__ inline bfu f2bf(float f) {
    union { float f; unsigned i; } c; c.f = f;
    unsigned x = c.i;
    return (bfu)((x + 0x7fffu + ((x >> 16) & 1u)) >> 16);
}
__device__ inline float blo(unsigned u) {
    union { unsigned i; float f; } c; c.i = u << 16; return c.f;
}
__device__ inline float bhi(unsigned u) {
    union { unsigned i; float f; } c; c.i = u & 0xffff0000u; return c.f;
}

// ---------------- bucket CSR fill (dst-partitioned, XCD affinity) ----------

__global__ void fill_csr_part(const int* __restrict__ ei, int* __restrict__ cursor,
                              int* __restrict__ srclist) {
    int p = blockIdx.x & 7;
    int b = blockIdx.x >> 3;
    int lo = p * PSZ, hi = lo + PSZ;
    int e0 = (b * 256 + threadIdx.x) * 4;
    if (e0 >= E_TOT) return;
    bool self = e0 >= E_IN;
    int4 d4;
    if (!self) d4 = *(const int4*)&ei[E_IN + e0];
    else { int bb = e0 - E_IN; d4 = make_int4(bb, bb + 1, bb + 2, bb + 3); }
    int dd[4] = {d4.x, d4.y, d4.z, d4.w};
    #pragma unroll
    for (int q = 0; q < 4; ++q) {
        int d = dd[q];
        if (d >= lo && d < hi) {
            int s = self ? (e0 - E_IN + q) : ei[e0 + q];
            int pos = atomicAdd(&cursor[d], 1);
            if (pos < CAP) srclist[d * CAP + pos] = s;
        }
    }
}

// ---------------- prep: W -> W^T bf16 ----------------

__global__ void transpose_w(const float* __restrict__ W1, const float* __restrict__ W2,
                            const float* __restrict__ W3,
                            bfu* __restrict__ Wt1, bfu* __restrict__ Wt2,
                            bfu* __restrict__ Wt3) {
    int idx = blockIdx.x * 256 + threadIdx.x;
    if (idx < 16384) {
        int k = idx >> 7, n = idx & 127;
        Wt1[n * 128 + k] = f2bf(W1[idx]);
    } else if (idx < 32768) {
        int r = idx - 16384;
        int k = r >> 7, n = r & 127;
        Wt2[n * 128 + k] = f2bf(W2[r]);
    } else if (idx < 32768 + 4096) {
        int r = idx - 32768;
        int k = r >> 5, n = r & 31;
        Wt3[n * 128 + k] = f2bf(W3[r]);
    }
}

// ---------------- MFMA GEMM: Y[N,COUT](bf16) = X[N,128] @ W ----------------

__device__ inline bf16x8 ldcvt_f32(const float* p) {
    float4 v0 = *(const float4*)p;
    float4 v1 = *(const float4*)(p + 4);
    bf16x8 a;
    a[0] = (short)f2bf(v0.x); a[1] = (short)f2bf(v0.y);
    a[2] = (short)f2bf(v0.z); a[3] = (short)f2bf(v0.w);
    a[4] = (short)f2bf(v1.x); a[5] = (short)f2bf(v1.y);
    a[6] = (short)f2bf(v1.z); a[7] = (short)f2bf(v1.w);
    return a;
}

template<int COUT, bool F32A>
__global__ __launch_bounds__(256) void gemm_mfma(const void* __restrict__ Xg_,
                                                 const bfu* __restrict__ Wt,
                                                 bfu* __restrict__ Y) {
    constexpr int NT = COUT / 16;
    int wid  = threadIdx.x >> 6;
    int lane = threadIdx.x & 63;
    int m = lane & 15, quad = lane >> 4;
    int rbase = (blockIdx.x * 4 + wid) * 16;
    if (rbase >= N_NODES) return;
    int rA = rbase + m; if (rA >= N_NODES) rA = N_NODES - 1;

    bf16x8 a0, a1, a2, a3;
    if constexpr (F32A) {
        const float* Ap = (const float*)Xg_ + (size_t)rA * 128 + quad * 8;
        a0 = ldcvt_f32(Ap);
        a1 = ldcvt_f32(Ap + 32);
        a2 = ldcvt_f32(Ap + 64);
        a3 = ldcvt_f32(Ap + 96);
    } else {
        const bfu* Ap = (const bfu*)Xg_ + (size_t)rA * 128 + quad * 8;
        a0 = *(const bf16x8*)(Ap);
        a1 = *(const bf16x8*)(Ap + 32);
        a2 = *(const bf16x8*)(Ap + 64);
        a3 = *(const bf16x8*)(Ap + 96);
    }

    const bfu* Bp = Wt + (size_t)m * 128 + quad * 8;
    f32x4 acc[NT];
    #pragma unroll
    for (int nt = 0; nt < NT; nt++) {
        const bfu* Bn = Bp + nt * 16 * 128;
        f32x4 c = {0.f, 0.f, 0.f, 0.f};
        c = __builtin_amdgcn_mfma_f32_16x16x32_bf16(a0, *(const bf16x8*)(Bn),      c, 0, 0, 0);
        c = __builtin_amdgcn_mfma_f32_16x16x32_bf16(a1, *(const bf16x8*)(Bn + 32), c, 0, 0, 0);
        c = __builtin_amdgcn_mfma_f32_16x16x32_bf16(a2, *(const bf16x8*)(Bn + 64), c, 0, 0, 0);
        c = __builtin_amdgcn_mfma_f32_16x16x32_bf16(a3, *(const bf16x8*)(Bn + 96), c, 0, 0, 0);
        acc[nt] = c;
    }
    #pragma unroll
    for (int nt = 0; nt < NT; nt++) {
        #pragma unroll
        for (int r = 0; r < 4; r++) {
            int row = rbase + quad * 4 + r;
            if (row < N_NODES)
                Y[(size_t)row * COUT + nt * 16 + m] = f2bf(acc[nt][r]);
        }
    }
}

// ---------------- per-node logit parts (bf16 h) ----------------

template<int H, int HID>
__global__ void logits_k(const bfu* __restrict__ Hb, const float* __restrict__ a_src,
                         const float* __restrict__ a_dst,
                         float* __restrict__ als, float* __restrict__ ald) {
    int id = blockIdx.x * 256 + threadIdx.x;
    if (id >= N_NODES * H) return;
    int n = id / H, h = id % H;
    const bfu* row = &Hb[(size_t)(n * H + h) * HID];
    float s = 0.f, dd = 0.f;
    #pragma unroll
    for (int j = 0; j < HID; j += 2) {
        unsigned u = *(const unsigned*)&row[j];
        float f0 = blo(u), f1 = bhi(u);
        s  += f0 * a_src[h * HID + j] + f1 * a_src[h * HID + j + 1];
        dd += f0 * a_dst[h * HID + j] + f1 * a_dst[h * HID + j + 1];
    }
    als[id] = s; ald[id] = dd;
}

// ---------------- aggregation (bucket list, unroll x4) ----------------
// agg128: 4 dst per wave; 16 lanes per dst; lane owns 8 channels (16B load).

__global__ __launch_bounds__(256) void agg128(const bfu* __restrict__ Hb,
        const float* __restrict__ als, const float* __restrict__ ald,
        const int* __restrict__ deg, const int* __restrict__ srclist,
        const float* __restrict__ bias, bfu* __restrict__ out) {
    int wave = (blockIdx.x * 256 + threadIdx.x) >> 6;
    int lane = threadIdx.x & 63;
    int sub  = lane >> 4;
    int li   = lane & 15;
    int d    = wave * 4 + sub;
    if (d >= N_NODES) return;
    int c0 = li * 8;
    int h  = li >> 1;
    float ad = ald[d * 8 + h];
    const int* sl = srclist + d * CAP;
    int n = deg[d];
    float a0=0.f,a1=0.f,a2=0.f,a3=0.f,a4=0.f,a5=0.f,a6=0.f,a7=0.f,den=0.f;
    int j = 0;
    for (; j + 4 <= n; j += 4) {
        int s0 = sl[j], s1 = sl[j+1], s2 = sl[j+2], s3 = sl[j+3];
        uint4 u0 = *(const uint4*)(Hb + (size_t)s0 * 128 + c0);
        uint4 u1 = *(const uint4*)(Hb + (size_t)s1 * 128 + c0);
        uint4 u2 = *(const uint4*)(Hb + (size_t)s2 * 128 + c0);
        uint4 u3 = *(const uint4*)(Hb + (size_t)s3 * 128 + c0);
        float x0 = als[s0*8+h], x1 = als[s1*8+h], x2 = als[s2*8+h], x3 = als[s3*8+h];
        float l0 = x0 + ad; l0 = fmaxf(l0, NEG*l0); float w0 = __expf(l0);
        float l1 = x1 + ad; l1 = fmaxf(l1, NEG*l1); float w1 = __expf(l1);
        float l2 = x2 + ad; l2 = fmaxf(l2, NEG*l2); float w2 = __expf(l2);
        float l3 = x3 + ad; l3 = fmaxf(l3, NEG*l3); float w3 = __expf(l3);
        den += (w0 + w1) + (w2 + w3);
        a0=fmaf(w0,blo(u0.x),a0); a1=fmaf(w0,bhi(u0.x),a1); a2=fmaf(w0,blo(u0.y),a2); a3=fmaf(w0,bhi(u0.y),a3);
        a4=fmaf(w0,blo(u0.z),a4); a5=fmaf(w0,bhi(u0.z),a5); a6=fmaf(w0,blo(u0.w),a6); a7=fmaf(w0,bhi(u0.w),a7);
        a0=fmaf(w1,blo(u1.x),a0); a1=fmaf(w1,bhi(u1.x),a1); a2=fmaf(w1,blo(u1.y),a2); a3=fmaf(w1,bhi(u1.y),a3);
        a4=fmaf(w1,blo(u1.z),a4); a5=fmaf(w1,bhi(u1.z),a5); a6=fmaf(w1,blo(u1.w),a6); a7=fmaf(w1,bhi(u1.w),a7);
        a0=fmaf(w2,blo(u2.x),a0); a1=fmaf(w2,bhi(u2.x),a1); a2=fmaf(w2,blo(u2.y),a2); a3=fmaf(w2,bhi(u2.y),a3);
        a4=fmaf(w2,blo(u2.z),a4); a5=fmaf(w2,bhi(u2.z),a5); a6=fmaf(w2,blo(u2.w),a6); a7=fmaf(w2,bhi(u2.w),a7);
        a0=fmaf(w3,blo(u3.x),a0); a1=fmaf(w3,bhi(u3.x),a1); a2=fmaf(w3,blo(u3.y),a2); a3=fmaf(w3,bhi(u3.y),a3);
        a4=fmaf(w3,blo(u3.z),a4); a5=fmaf(w3,bhi(u3.z),a5); a6=fmaf(w3,blo(u3.w),a6); a7=fmaf(w3,bhi(u3.w),a7);
    }
    for (; j < n; ++j) {
        int s0 = sl[j];
        uint4 u0 = *(const uint4*)(Hb + (size_t)s0 * 128 + c0);
        float x0 = als[s0*8+h];
        float l0 = x0 + ad; l0 = fmaxf(l0, NEG*l0); float w0 = __expf(l0);
        den += w0;
        a0=fmaf(w0,blo(u0.x),a0); a1=fmaf(w0,bhi(u0.x),a1); a2=fmaf(w0,blo(u0.y),a2); a3=fmaf(w0,bhi(u0.y),a3);
        a4=fmaf(w0,blo(u0.z),a4); a5=fmaf(w0,bhi(u0.z),a5); a6=fmaf(w0,blo(u0.w),a6); a7=fmaf(w0,bhi(u0.w),a7);
    }
    float r = 1.f / den;
    float4 b0 = *(const float4*)&bias[c0];
    float4 b1 = *(const float4*)&bias[c0 + 4];
    float o0 = fmaxf(fmaf(a0, r, b0.x), 0.f);
    float o1 = fmaxf(fmaf(a1, r, b0.y), 0.f);
    float o2 = fmaxf(fmaf(a2, r, b0.z), 0.f);
    float o3 = fmaxf(fmaf(a3, r, b0.w), 0.f);
    float o4 = fmaxf(fmaf(a4, r, b1.x), 0.f);
    float o5 = fmaxf(fmaf(a5, r, b1.y), 0.f);
    float o6 = fmaxf(fmaf(a6, r, b1.z), 0.f);
    float o7 = fmaxf(fmaf(a7, r, b1.w), 0.f);
    uint4 st;
    st.x = (unsigned)f2bf(o0) | ((unsigned)f2bf(o1) << 16);
    st.y = (unsigned)f2bf(o2) | ((unsigned)f2bf(o3) << 16);
    st.z = (unsigned)f2bf(o4) | ((unsigned)f2bf(o5) << 16);
    st.w = (unsigned)f2bf(o6) | ((unsigned)f2bf(o7) << 16);
    *(uint4*)&out[(size_t)d * 128 + c0] = st;
}

// agg32: 8 dst per wave; 8 lanes per dst; lane owns 4 channels (8B load).
__global__ __launch_bounds__(256) void agg32(const bfu* __restrict__ Hb,
        const float* __restrict__ als, const float* __restrict__ ald,
        const int* __restrict__ deg, const int* __restrict__ srclist,
        const float* __restrict__ bias, float* __restrict__ out) {
    int wave = (blockIdx.x * 256 + threadIdx.x) >> 6;
    int lane = threadIdx.x & 63;
    int sub  = lane >> 3;
    int li   = lane & 7;
    int d    = wave * 8 + sub;
    if (d >= N_NODES) return;
    int c0 = li * 4;
    float adv = ald[d];
    const int* sl = srclist + d * CAP;
    int n = deg[d];
    float a0=0.f,a1=0.f,a2=0.f,a3=0.f,den=0.f;
    int j = 0;
    for (; j + 4 <= n; j += 4) {
        int s0 = sl[j], s1 = sl[j+1], s2 = sl[j+2], s3 = sl[j+3];
        uint2 u0 = *(const uint2*)(Hb + (size_t)s0 * 32 + c0);
        uint2 u1 = *(const uint2*)(Hb + (size_t)s1 * 32 + c0);
        uint2 u2 = *(const uint2*)(Hb + (size_t)s2 * 32 + c0);
        uint2 u3 = *(const uint2*)(Hb + (size_t)s3 * 32 + c0);
        float x0 = als[s0], x1 = als[s1], x2 = als[s2], x3 = als[s3];
        float l0 = x0 + adv; l0 = fmaxf(l0, NEG*l0); float w0 = __expf(l0);
        float l1 = x1 + adv; l1 = fmaxf(l1, NEG*l1); float w1 = __expf(l1);
        float l2 = x2 + adv; l2 = fmaxf(l2, NEG*l2); float w2 = __expf(l2);
        float l3 = x3 + adv; l3 = fmaxf(l3, NEG*l3); float w3 = __expf(l3);
        den += (w0 + w1) + (w2 + w3);
        a0=fmaf(w0,blo(u0.x),a0); a1=fmaf(w0,bhi(u0.x),a1); a2=fmaf(w0,blo(u0.y),a2); a3=fmaf(w0,bhi(u0.y),a3);
        a0=fmaf(w1,blo(u1.x),a0); a1=fmaf(w1,bhi(u1.x),a1); a2=fmaf(w1,blo(u1.y),a2); a3=fmaf(w1,bhi(u1.y),a3);
        a0=fmaf(w2,blo(u2.x),a0); a1=fmaf(w2,bhi(u2.x),a1); a2=fmaf(w2,blo(u2.y),a2); a3=fmaf(w2,bhi(u2.y),a3);
        a0=fmaf(w3,blo(u3.x),a0); a1=fmaf(w3,bhi(u3.x),a1); a2=fmaf(w3,blo(u3.y),a2); a3=fmaf(w3,bhi(u3.y),a3);
    }
    for (; j < n; ++j) {
        int s0 = sl[j];
        uint2 u0 = *(const uint2*)(Hb + (size_t)s0 * 32 + c0);
        float x0 = als[s0];
        float l0 = x0 + adv; l0 = fmaxf(l0, NEG*l0); float w0 = __expf(l0);
        den += w0;
        a0=fmaf(w0,blo(u0.x),a0); a1=fmaf(w0,bhi(u0.x),a1); a2=fmaf(w0,blo(u0.y),a2); a3=fmaf(w0,bhi(u0.y),a3);
    }
    float r = 1.f / den;
    float4 bv = *(const float4*)&bias[c0];
    float4 o;
    o.x = fmaf(a0, r, bv.x); o.y = fmaf(a1, r, bv.y);
    o.z = fmaf(a2, r, bv.z); o.w = fmaf(a3, r, bv.w);
    *(float4*)&out[(size_t)d * 32 + c0] = o;
}

// ---------------- global mean pool ----------------
__global__ void pool32(const float* __restrict__ h3, float* __restrict__ outp) {
    __shared__ float lds[256];
    int t = threadIdx.x;
    int c = t & 31, g = t >> 5;
    float acc = 0.f;
    for (int n = blockIdx.x * 8 + g; n < N_NODES; n += gridDim.x * 8)
        acc += h3[n * 32 + c];
    lds[t] = acc;
    __syncthreads();
    if (g == 0) {
        float s = 0.f;
        for (int gg = 0; gg < 8; ++gg) s += lds[gg * 32 + c];
        atomicAdd(&outp[c], s * (1.0f / N_NODES));
    }
}

// ---------------- launch ----------------

extern "C" void kernel_launch(void* const* d_in, const int* in_sizes, int n_in,
                              void* d_out, int out_size, void* d_ws, size_t ws_size,
                              hipStream_t stream) {
    (void)in_sizes; (void)n_in; (void)out_size; (void)ws_size;
    const float* x   = (const float*)d_in[0];
    const int*   ei  = (const int*)d_in[1];
    const float* W1  = (const float*)d_in[2];
    const float* as1 = (const float*)d_in[3];
    const float* ad1 = (const float*)d_in[4];
    const float* b1  = (const float*)d_in[5];
    const float* W2  = (const float*)d_in[6];
    const float* as2 = (const float*)d_in[7];
    const float* ad2 = (const float*)d_in[8];
    const float* b2  = (const float*)d_in[9];
    const float* W3  = (const float*)d_in[10];
    const float* as3 = (const float*)d_in[11];
    const float* ad3 = (const float*)d_in[12];
    const float* b3  = (const float*)d_in[13];

    char* ws = (char*)d_ws;
    size_t off = 0;
    auto carve = [&](size_t bytes) { void* p = ws + off; off += (bytes + 255) & ~size_t(255); return p; };
    bfu*   bufH    = (bfu*)carve(size_t(N_NODES) * 128 * 2);
    bfu*   bufF    = (bfu*)carve(size_t(N_NODES) * 128 * 2);
    float* out3    = (float*)carve(size_t(N_NODES) * 32 * 4);
    float* als     = (float*)carve(size_t(N_NODES) * 8 * 4);
    float* ald     = (float*)carve(size_t(N_NODES) * 8 * 4);
    int*   cursor  = (int*)carve(size_t(N_NODES) * 4);
    bfu*   Wt1     = (bfu*)carve(128 * 128 * 2);
    bfu*   Wt2     = (bfu*)carve(128 * 128 * 2);
    bfu*   Wt3     = (bfu*)carve(32 * 128 * 2);
    int*   srclist = (int*)carve(size_t(N_NODES) * CAP * 4);

    const int EDGE_B4 = (E_TOT / 4 + 255) / 256;   // 1661
    const int GEMM_B  = (N_NODES + 63) / 64;

    hipMemsetAsync(cursor, 0, size_t(N_NODES) * 4, stream);
    hipMemsetAsync(d_out, 0, 32 * 4, stream);

    transpose_w<<<(36864 + 255) / 256, 256, 0, stream>>>(W1, W2, W3, Wt1, Wt2, Wt3);
    fill_csr_part<<<EDGE_B4 * P_XCD, 256, 0, stream>>>(ei, cursor, srclist);

    // layer 1 (fp32 A, cvt in register)
    gemm_mfma<128, true><<<GEMM_B, 256, 0, stream>>>(x, Wt1, bufH);
    logits_k<8, 16><<<(N_NODES * 8 + 255) / 256, 256, 0, stream>>>(bufH, as1, ad1, als, ald);
    agg128<<<(N_NODES + 15) / 16, 256, 0, stream>>>(bufH, als, ald, cursor, srclist, b1, bufF);

    // layer 2
    gemm_mfma<128, false><<<GEMM_B, 256, 0, stream>>>(bufF, Wt2, bufH);
    logits_k<8, 16><<<(N_NODES * 8 + 255) / 256, 256, 0, stream>>>(bufH, as2, ad2, als, ald);
    agg128<<<(N_NODES + 15) / 16, 256, 0, stream>>>(bufH, als, ald, cursor, srclist, b2, bufF);

    // layer 3
    gemm_mfma<32, false><<<GEMM_B, 256, 0, stream>>>(bufF, Wt3, bufH);
    logits_k<1, 32><<<(N_NODES + 255) / 256, 256, 0, stream>>>(bufH, as3, ad3, als, ald);
    agg32<<<(N_NODES + 31) / 32, 256, 0, stream>>>(bufH, als, ald, cursor, srclist, b3, out3);
    pool32<<<64, 256, 0, stream>>>(out3, (float*)d_out);
}

// Round 8
// 511.767 us; speedup vs baseline: 1.6722x; 1.0283x over previous
//
#include <hip/hip_runtime.h>

// GAT (3-layer) on MI355X.
// R7: (a) h stored fp8 e4m3 (HW cvt) -> agg gather rows 256B->128B. R6 showed
//     agg128 pinned at an L2-miss bandwidth ceiling (275MB @ ~3.7TB/s = its
//     whole 84us; unroll x4 changed nothing) -- only bytes/edge helps.
//     (b) logits fused into GEMM epilogue (head==nt, ch==m in C/D layout;
//     16-lane shfl_xor butterflies over fp32 acc) -- 3 kernels gone.
//     (c) mean-pool fused into agg32 (block partials, tiny final reduce);
//     out3 never touches HBM.

typedef unsigned short bfu;
typedef unsigned char u8;
typedef __attribute__((ext_vector_type(8))) short bf16x8;
typedef __attribute__((ext_vector_type(4))) float f32x4;
typedef __attribute__((ext_vector_type(2))) float f32x2;

constexpr int N_NODES = 100000;
constexpr int E_IN    = 1600000;
constexpr int E_TOT   = E_IN + N_NODES;   // + self loops
constexpr float NEG   = 0.2f;
constexpr int P_XCD   = 8;
constexpr int PSZ     = N_NODES / P_XCD;  // 12500
constexpr int CAP     = 64;               // bucket slots/node (Poisson(16)+1)
constexpr int AGG32_B = N_NODES / 32;     // 3125 blocks, exact

__device__ inline bfu f2bf(float f) {
    union { float f; unsigned i; } c; c.f = f;
    unsigned x = c.i;
    return (bfu)((x + 0x7fffu + ((x >> 16) & 1u)) >> 16);
}
__device__ inline float blo(unsigned u) {
    union { unsigned i; float f; } c; c.i = u << 16; return c.f;
}
__device__ inline float bhi(unsigned u) {
    union { unsigned i; float f; } c; c.i = u & 0xffff0000u; return c.f;
}
__device__ inline u8 f2fp8(float f) {
    return (u8)(__builtin_amdgcn_cvt_pk_fp8_f32(f, f, 0, false) & 0xff);
}

// ---------------- bucket CSR fill (dst-partitioned, XCD affinity) ----------

__global__ void fill_csr_part(const int* __restrict__ ei, int* __restrict__ cursor,
                              int* __restrict__ srclist) {
    int p = blockIdx.x & 7;
    int b = blockIdx.x >> 3;
    int lo = p * PSZ, hi = lo + PSZ;
    int e0 = (b * 256 + threadIdx.x) * 4;
    if (e0 >= E_TOT) return;
    bool self = e0 >= E_IN;
    int4 d4;
    if (!self) d4 = *(const int4*)&ei[E_IN + e0];
    else { int bb = e0 - E_IN; d4 = make_int4(bb, bb + 1, bb + 2, bb + 3); }
    int dd[4] = {d4.x, d4.y, d4.z, d4.w};
    #pragma unroll
    for (int q = 0; q < 4; ++q) {
        int d = dd[q];
        if (d >= lo && d < hi) {
            int s = self ? (e0 - E_IN + q) : ei[e0 + q];
            int pos = atomicAdd(&cursor[d], 1);
            if (pos < CAP) srclist[d * CAP + pos] = s;
        }
    }
}

// ---------------- prep: W -> W^T bf16 ----------------

__global__ void transpose_w(const float* __restrict__ W1, const float* __restrict__ W2,
                            const float* __restrict__ W3,
                            bfu* __restrict__ Wt1, bfu* __restrict__ Wt2,
                            bfu* __restrict__ Wt3) {
    int idx = blockIdx.x * 256 + threadIdx.x;
    if (idx < 16384) {
        int k = idx >> 7, n = idx & 127;
        Wt1[n * 128 + k] = f2bf(W1[idx]);
    } else if (idx < 32768) {
        int r = idx - 16384;
        int k = r >> 7, n = r & 127;
        Wt2[n * 128 + k] = f2bf(W2[r]);
    } else if (idx < 32768 + 4096) {
        int r = idx - 32768;
        int k = r >> 5, n = r & 31;
        Wt3[n * 128 + k] = f2bf(W3[r]);
    }
}

// ---------------- MFMA GEMM + fused logits; fp8 h output --------------------
// Y_fp8[row, col] = fp8(X @ W); als/ald computed from fp32 acc in-register.
// C/D layout: row = quad*4+r, col = nt*16+m -> head = nt (HID=16), ch = m.

__device__ inline bf16x8 ldcvt_f32(const float* p) {
    float4 v0 = *(const float4*)p;
    float4 v1 = *(const float4*)(p + 4);
    bf16x8 a;
    a[0] = (short)f2bf(v0.x); a[1] = (short)f2bf(v0.y);
    a[2] = (short)f2bf(v0.z); a[3] = (short)f2bf(v0.w);
    a[4] = (short)f2bf(v1.x); a[5] = (short)f2bf(v1.y);
    a[6] = (short)f2bf(v1.z); a[7] = (short)f2bf(v1.w);
    return a;
}

template<int COUT, bool F32A, int H>
__global__ __launch_bounds__(256) void gemm_mfma(const void* __restrict__ Xg_,
                                                 const bfu* __restrict__ Wt,
                                                 const float* __restrict__ a_src,
                                                 const float* __restrict__ a_dst,
                                                 u8* __restrict__ Y,
                                                 float* __restrict__ als,
                                                 float* __restrict__ ald) {
    constexpr int NT = COUT / 16;
    int wid  = threadIdx.x >> 6;
    int lane = threadIdx.x & 63;
    int m = lane & 15, quad = lane >> 4;
    int rbase = (blockIdx.x * 4 + wid) * 16;
    if (rbase >= N_NODES) return;
    int rA = rbase + m; if (rA >= N_NODES) rA = N_NODES - 1;

    bf16x8 a0, a1, a2, a3;
    if constexpr (F32A) {
        const float* Ap = (const float*)Xg_ + (size_t)rA * 128 + quad * 8;
        a0 = ldcvt_f32(Ap);
        a1 = ldcvt_f32(Ap + 32);
        a2 = ldcvt_f32(Ap + 64);
        a3 = ldcvt_f32(Ap + 96);
    } else {
        const bfu* Ap = (const bfu*)Xg_ + (size_t)rA * 128 + quad * 8;
        a0 = *(const bf16x8*)(Ap);
        a1 = *(const bf16x8*)(Ap + 32);
        a2 = *(const bf16x8*)(Ap + 64);
        a3 = *(const bf16x8*)(Ap + 96);
    }

    const bfu* Bp = Wt + (size_t)m * 128 + quad * 8;
    f32x4 acc[NT];
    #pragma unroll
    for (int nt = 0; nt < NT; nt++) {
        const bfu* Bn = Bp + nt * 16 * 128;
        f32x4 c = {0.f, 0.f, 0.f, 0.f};
        c = __builtin_amdgcn_mfma_f32_16x16x32_bf16(a0, *(const bf16x8*)(Bn),      c, 0, 0, 0);
        c = __builtin_amdgcn_mfma_f32_16x16x32_bf16(a1, *(const bf16x8*)(Bn + 32), c, 0, 0, 0);
        c = __builtin_amdgcn_mfma_f32_16x16x32_bf16(a2, *(const bf16x8*)(Bn + 64), c, 0, 0, 0);
        c = __builtin_amdgcn_mfma_f32_16x16x32_bf16(a3, *(const bf16x8*)(Bn + 96), c, 0, 0, 0);
        acc[nt] = c;
    }

    // fp8 store
    #pragma unroll
    for (int nt = 0; nt < NT; nt++) {
        #pragma unroll
        for (int r = 0; r < 4; r++) {
            int row = rbase + quad * 4 + r;
            if (row < N_NODES)
                Y[(size_t)row * COUT + nt * 16 + m] = f2fp8(acc[nt][r]);
        }
    }

    // fused logits
    if constexpr (H == 8) {
        #pragma unroll
        for (int nt = 0; nt < NT; nt++) {
            float as_ = a_src[nt * 16 + m];
            float ad_ = a_dst[nt * 16 + m];
            #pragma unroll
            for (int r = 0; r < 4; r++) {
                float vs = acc[nt][r] * as_;
                float vd = acc[nt][r] * ad_;
                #pragma unroll
                for (int mask = 1; mask < 16; mask <<= 1) {
                    vs += __shfl_xor(vs, mask);
                    vd += __shfl_xor(vd, mask);
                }
                int row = rbase + quad * 4 + r;
                if (m == 0 && row < N_NODES) {
                    als[row * 8 + nt] = vs;
                    ald[row * 8 + nt] = vd;
                }
            }
        }
    } else {  // H == 1, HID == 32, NT == 2
        float as0 = a_src[m], as1 = a_src[16 + m];
        float ad0 = a_dst[m], ad1 = a_dst[16 + m];
        #pragma unroll
        for (int r = 0; r < 4; r++) {
            float vs = acc[0][r] * as0 + acc[1][r] * as1;
            float vd = acc[0][r] * ad0 + acc[1][r] * ad1;
            #pragma unroll
            for (int mask = 1; mask < 16; mask <<= 1) {
                vs += __shfl_xor(vs, mask);
                vd += __shfl_xor(vd, mask);
            }
            int row = rbase + quad * 4 + r;
            if (m == 0 && row < N_NODES) {
                als[row] = vs;
                ald[row] = vd;
            }
        }
    }
}

// ---------------- aggregation (fp8 gather, bucket list, unroll x4) ----------
// agg128: 4 dst per wave; 16 lanes per dst; lane owns 8 channels (8B fp8 load).

__global__ __launch_bounds__(256) void agg128(const u8* __restrict__ Hb,
        const float* __restrict__ als, const float* __restrict__ ald,
        const int* __restrict__ deg, const int* __restrict__ srclist,
        const float* __restrict__ bias, bfu* __restrict__ out) {
    int wave = (blockIdx.x * 256 + threadIdx.x) >> 6;
    int lane = threadIdx.x & 63;
    int sub  = lane >> 4;
    int li   = lane & 15;
    int d    = wave * 4 + sub;
    if (d >= N_NODES) return;
    int c0 = li * 8;
    int h  = li >> 1;
    float ad = ald[d * 8 + h];
    const int* sl = srclist + d * CAP;
    int n = deg[d];
    float a0=0.f,a1=0.f,a2=0.f,a3=0.f,a4=0.f,a5=0.f,a6=0.f,a7=0.f,den=0.f;
    int j = 0;
    for (; j + 4 <= n; j += 4) {
        int s0 = sl[j], s1 = sl[j+1], s2 = sl[j+2], s3 = sl[j+3];
        uint2 u0 = *(const uint2*)(Hb + (size_t)s0 * 128 + c0);
        uint2 u1 = *(const uint2*)(Hb + (size_t)s1 * 128 + c0);
        uint2 u2 = *(const uint2*)(Hb + (size_t)s2 * 128 + c0);
        uint2 u3 = *(const uint2*)(Hb + (size_t)s3 * 128 + c0);
        float x0 = als[s0*8+h], x1 = als[s1*8+h], x2 = als[s2*8+h], x3 = als[s3*8+h];
        float l0 = x0 + ad; l0 = fmaxf(l0, NEG*l0); float w0 = __expf(l0);
        float l1 = x1 + ad; l1 = fmaxf(l1, NEG*l1); float w1 = __expf(l1);
        float l2 = x2 + ad; l2 = fmaxf(l2, NEG*l2); float w2 = __expf(l2);
        float l3 = x3 + ad; l3 = fmaxf(l3, NEG*l3); float w3 = __expf(l3);
        den += (w0 + w1) + (w2 + w3);
        {
            f32x2 p0 = __builtin_amdgcn_cvt_pk_f32_fp8((int)u0.x, false);
            f32x2 p1 = __builtin_amdgcn_cvt_pk_f32_fp8((int)u0.x, true);
            f32x2 p2 = __builtin_amdgcn_cvt_pk_f32_fp8((int)u0.y, false);
            f32x2 p3 = __builtin_amdgcn_cvt_pk_f32_fp8((int)u0.y, true);
            a0=fmaf(w0,p0[0],a0); a1=fmaf(w0,p0[1],a1); a2=fmaf(w0,p1[0],a2); a3=fmaf(w0,p1[1],a3);
            a4=fmaf(w0,p2[0],a4); a5=fmaf(w0,p2[1],a5); a6=fmaf(w0,p3[0],a6); a7=fmaf(w0,p3[1],a7);
        }
        {
            f32x2 p0 = __builtin_amdgcn_cvt_pk_f32_fp8((int)u1.x, false);
            f32x2 p1 = __builtin_amdgcn_cvt_pk_f32_fp8((int)u1.x, true);
            f32x2 p2 = __builtin_amdgcn_cvt_pk_f32_fp8((int)u1.y, false);
            f32x2 p3 = __builtin_amdgcn_cvt_pk_f32_fp8((int)u1.y, true);
            a0=fmaf(w1,p0[0],a0); a1=fmaf(w1,p0[1],a1); a2=fmaf(w1,p1[0],a2); a3=fmaf(w1,p1[1],a3);
            a4=fmaf(w1,p2[0],a4); a5=fmaf(w1,p2[1],a5); a6=fmaf(w1,p3[0],a6); a7=fmaf(w1,p3[1],a7);
        }
        {
            f32x2 p0 = __builtin_amdgcn_cvt_pk_f32_fp8((int)u2.x, false);
            f32x2 p1 = __builtin_amdgcn_cvt_pk_f32_fp8((int)u2.x, true);
            f32x2 p2 = __builtin_amdgcn_cvt_pk_f32_fp8((int)u2.y, false);
            f32x2 p3 = __builtin_amdgcn_cvt_pk_f32_fp8((int)u2.y, true);
            a0=fmaf(w2,p0[0],a0); a1=fmaf(w2,p0[1],a1); a2=fmaf(w2,p1[0],a2); a3=fmaf(w2,p1[1],a3);
            a4=fmaf(w2,p2[0],a4); a5=fmaf(w2,p2[1],a5); a6=fmaf(w2,p3[0],a6); a7=fmaf(w2,p3[1],a7);
        }
        {
            f32x2 p0 = __builtin_amdgcn_cvt_pk_f32_fp8((int)u3.x, false);
            f32x2 p1 = __builtin_amdgcn_cvt_pk_f32_fp8((int)u3.x, true);
            f32x2 p2 = __builtin_amdgcn_cvt_pk_f32_fp8((int)u3.y, false);
            f32x2 p3 = __builtin_amdgcn_cvt_pk_f32_fp8((int)u3.y, true);
            a0=fmaf(w3,p0[0],a0); a1=fmaf(w3,p0[1],a1); a2=fmaf(w3,p1[0],a2); a3=fmaf(w3,p1[1],a3);
            a4=fmaf(w3,p2[0],a4); a5=fmaf(w3,p2[1],a5); a6=fmaf(w3,p3[0],a6); a7=fmaf(w3,p3[1],a7);
        }
    }
    for (; j < n; ++j) {
        int s0 = sl[j];
        uint2 u0 = *(const uint2*)(Hb + (size_t)s0 * 128 + c0);
        float x0 = als[s0*8+h];
        float l0 = x0 + ad; l0 = fmaxf(l0, NEG*l0); float w0 = __expf(l0);
        den += w0;
        f32x2 p0 = __builtin_amdgcn_cvt_pk_f32_fp8((int)u0.x, false);
        f32x2 p1 = __builtin_amdgcn_cvt_pk_f32_fp8((int)u0.x, true);
        f32x2 p2 = __builtin_amdgcn_cvt_pk_f32_fp8((int)u0.y, false);
        f32x2 p3 = __builtin_amdgcn_cvt_pk_f32_fp8((int)u0.y, true);
        a0=fmaf(w0,p0[0],a0); a1=fmaf(w0,p0[1],a1); a2=fmaf(w0,p1[0],a2); a3=fmaf(w0,p1[1],a3);
        a4=fmaf(w0,p2[0],a4); a5=fmaf(w0,p2[1],a5); a6=fmaf(w0,p3[0],a6); a7=fmaf(w0,p3[1],a7);
    }
    float r = 1.f / den;
    float4 b0 = *(const float4*)&bias[c0];
    float4 b1 = *(const float4*)&bias[c0 + 4];
    float o0 = fmaxf(fmaf(a0, r, b0.x), 0.f);
    float o1 = fmaxf(fmaf(a1, r, b0.y), 0.f);
    float o2 = fmaxf(fmaf(a2, r, b0.z), 0.f);
    float o3 = fmaxf(fmaf(a3, r, b0.w), 0.f);
    float o4 = fmaxf(fmaf(a4, r, b1.x), 0.f);
    float o5 = fmaxf(fmaf(a5, r, b1.y), 0.f);
    float o6 = fmaxf(fmaf(a6, r, b1.z), 0.f);
    float o7 = fmaxf(fmaf(a7, r, b1.w), 0.f);
    uint4 st;
    st.x = (unsigned)f2bf(o0) | ((unsigned)f2bf(o1) << 16);
    st.y = (unsigned)f2bf(o2) | ((unsigned)f2bf(o3) << 16);
    st.z = (unsigned)f2bf(o4) | ((unsigned)f2bf(o5) << 16);
    st.w = (unsigned)f2bf(o6) | ((unsigned)f2bf(o7) << 16);
    *(uint4*)&out[(size_t)d * 128 + c0] = st;
}

// agg32 + fused pool partials: 8 dst/wave, 8 lanes/dst, lane owns 4 ch (4B fp8).
__global__ __launch_bounds__(256) void agg32(const u8* __restrict__ Hb,
        const float* __restrict__ als, const float* __restrict__ ald,
        const int* __restrict__ deg, const int* __restrict__ srclist,
        const float* __restrict__ bias, float* __restrict__ blockpart) {
    __shared__ float lds[4][32];
    int t    = threadIdx.x;
    int wid  = t >> 6;
    int lane = t & 63;
    int sub  = lane >> 3;
    int li   = lane & 7;
    int d    = blockIdx.x * 32 + wid * 8 + sub;   // exact: N_NODES % 32 == 0
    int c0 = li * 4;
    float adv = ald[d];
    const int* sl = srclist + d * CAP;
    int n = deg[d];
    float a0=0.f,a1=0.f,a2=0.f,a3=0.f,den=0.f;
    int j = 0;
    for (; j + 4 <= n; j += 4) {
        int s0 = sl[j], s1 = sl[j+1], s2 = sl[j+2], s3 = sl[j+3];
        unsigned u0 = *(const unsigned*)(Hb + (size_t)s0 * 32 + c0);
        unsigned u1 = *(const unsigned*)(Hb + (size_t)s1 * 32 + c0);
        unsigned u2 = *(const unsigned*)(Hb + (size_t)s2 * 32 + c0);
        unsigned u3 = *(const unsigned*)(Hb + (size_t)s3 * 32 + c0);
        float x0 = als[s0], x1 = als[s1], x2 = als[s2], x3 = als[s3];
        float l0 = x0 + adv; l0 = fmaxf(l0, NEG*l0); float w0 = __expf(l0);
        float l1 = x1 + adv; l1 = fmaxf(l1, NEG*l1); float w1 = __expf(l1);
        float l2 = x2 + adv; l2 = fmaxf(l2, NEG*l2); float w2 = __expf(l2);
        float l3 = x3 + adv; l3 = fmaxf(l3, NEG*l3); float w3 = __expf(l3);
        den += (w0 + w1) + (w2 + w3);
        f32x2 p;
        p = __builtin_amdgcn_cvt_pk_f32_fp8((int)u0, false); a0=fmaf(w0,p[0],a0); a1=fmaf(w0,p[1],a1);
        p = __builtin_amdgcn_cvt_pk_f32_fp8((int)u0, true);  a2=fmaf(w0,p[0],a2); a3=fmaf(w0,p[1],a3);
        p = __builtin_amdgcn_cvt_pk_f32_fp8((int)u1, false); a0=fmaf(w1,p[0],a0); a1=fmaf(w1,p[1],a1);
        p = __builtin_amdgcn_cvt_pk_f32_fp8((int)u1, true);  a2=fmaf(w1,p[0],a2); a3=fmaf(w1,p[1],a3);
        p = __builtin_amdgcn_cvt_pk_f32_fp8((int)u2, false); a0=fmaf(w2,p[0],a0); a1=fmaf(w2,p[1],a1);
        p = __builtin_amdgcn_cvt_pk_f32_fp8((int)u2, true);  a2=fmaf(w2,p[0],a2); a3=fmaf(w2,p[1],a3);
        p = __builtin_amdgcn_cvt_pk_f32_fp8((int)u3, false); a0=fmaf(w3,p[0],a0); a1=fmaf(w3,p[1],a1);
        p = __builtin_amdgcn_cvt_pk_f32_fp8((int)u3, true);  a2=fmaf(w3,p[0],a2); a3=fmaf(w3,p[1],a3);
    }
    for (; j < n; ++j) {
        int s0 = sl[j];
        unsigned u0 = *(const unsigned*)(Hb + (size_t)s0 * 32 + c0);
        float x0 = als[s0];
        float l0 = x0 + adv; l0 = fmaxf(l0, NEG*l0); float w0 = __expf(l0);
        den += w0;
        f32x2 p;
        p = __builtin_amdgcn_cvt_pk_f32_fp8((int)u0, false); a0=fmaf(w0,p[0],a0); a1=fmaf(w0,p[1],a1);
        p = __builtin_amdgcn_cvt_pk_f32_fp8((int)u0, true);  a2=fmaf(w0,p[0],a2); a3=fmaf(w0,p[1],a3);
    }
    float r = 1.f / den;
    float4 bv = *(const float4*)&bias[c0];
    float o0 = fmaf(a0, r, bv.x), o1 = fmaf(a1, r, bv.y);
    float o2 = fmaf(a2, r, bv.z), o3 = fmaf(a3, r, bv.w);
    // reduce over the 8 dst subs within the wave
    #pragma unroll
    for (int mask = 8; mask < 64; mask <<= 1) {
        o0 += __shfl_xor(o0, mask);
        o1 += __shfl_xor(o1, mask);
        o2 += __shfl_xor(o2, mask);
        o3 += __shfl_xor(o3, mask);
    }
    if (sub == 0) {
        lds[wid][c0]     = o0;
        lds[wid][c0 + 1] = o1;
        lds[wid][c0 + 2] = o2;
        lds[wid][c0 + 3] = o3;
    }
    __syncthreads();
    if (t < 32)
        blockpart[(size_t)blockIdx.x * 32 + t] =
            lds[0][t] + lds[1][t] + lds[2][t] + lds[3][t];
}

__global__ void pool_final(const float* __restrict__ blockpart, float* __restrict__ outp) {
    __shared__ float lds[256];
    int t = threadIdx.x;
    int c = t & 31, g = t >> 5;
    float s = 0.f;
    for (int b = g; b < AGG32_B; b += 8)
        s += blockpart[(size_t)b * 32 + c];
    lds[t] = s;
    __syncthreads();
    if (g == 0) {
        float tot = 0.f;
        #pragma unroll
        for (int gg = 0; gg < 8; ++gg) tot += lds[gg * 32 + c];
        outp[c] = tot * (1.0f / N_NODES);
    }
}

// ---------------- launch ----------------

extern "C" void kernel_launch(void* const* d_in, const int* in_sizes, int n_in,
                              void* d_out, int out_size, void* d_ws, size_t ws_size,
                              hipStream_t stream) {
    (void)in_sizes; (void)n_in; (void)out_size; (void)ws_size;
    const float* x   = (const float*)d_in[0];
    const int*   ei  = (const int*)d_in[1];
    const float* W1  = (const float*)d_in[2];
    const float* as1 = (const float*)d_in[3];
    const float* ad1 = (const float*)d_in[4];
    const float* b1  = (const float*)d_in[5];
    const float* W2  = (const float*)d_in[6];
    const float* as2 = (const float*)d_in[7];
    const float* ad2 = (const float*)d_in[8];
    const float* b2  = (const float*)d_in[9];
    const float* W3  = (const float*)d_in[10];
    const float* as3 = (const float*)d_in[11];
    const float* ad3 = (const float*)d_in[12];
    const float* b3  = (const float*)d_in[13];

    char* ws = (char*)d_ws;
    size_t off = 0;
    auto carve = [&](size_t bytes) { void* p = ws + off; off += (bytes + 255) & ~size_t(255); return p; };
    u8*    bufH    = (u8*)carve(size_t(N_NODES) * 128);        // h (fp8 e4m3)
    bfu*   bufF    = (bfu*)carve(size_t(N_NODES) * 128 * 2);   // agg out (bf16)
    float* als     = (float*)carve(size_t(N_NODES) * 8 * 4);
    float* ald     = (float*)carve(size_t(N_NODES) * 8 * 4);
    int*   cursor  = (int*)carve(size_t(N_NODES) * 4);
    bfu*   Wt1     = (bfu*)carve(128 * 128 * 2);
    bfu*   Wt2     = (bfu*)carve(128 * 128 * 2);
    bfu*   Wt3     = (bfu*)carve(32 * 128 * 2);
    float* bpart   = (float*)carve(size_t(AGG32_B) * 32 * 4);
    int*   srclist = (int*)carve(size_t(N_NODES) * CAP * 4);

    const int EDGE_B4 = (E_TOT / 4 + 255) / 256;   // 1661
    const int GEMM_B  = (N_NODES + 63) / 64;

    hipMemsetAsync(cursor, 0, size_t(N_NODES) * 4, stream);

    transpose_w<<<(36864 + 255) / 256, 256, 0, stream>>>(W1, W2, W3, Wt1, Wt2, Wt3);
    fill_csr_part<<<EDGE_B4 * P_XCD, 256, 0, stream>>>(ei, cursor, srclist);

    // layer 1 (fp32 A, cvt in register)
    gemm_mfma<128, true, 8><<<GEMM_B, 256, 0, stream>>>(x, Wt1, as1, ad1, bufH, als, ald);
    agg128<<<(N_NODES + 15) / 16, 256, 0, stream>>>(bufH, als, ald, cursor, srclist, b1, bufF);

    // layer 2
    gemm_mfma<128, false, 8><<<GEMM_B, 256, 0, stream>>>(bufF, Wt2, as2, ad2, bufH, als, ald);
    agg128<<<(N_NODES + 15) / 16, 256, 0, stream>>>(bufH, als, ald, cursor, srclist, b2, bufF);

    // layer 3
    gemm_mfma<32, false, 1><<<GEMM_B, 256, 0, stream>>>(bufF, Wt3, as3, ad3, bufH, als, ald);
    agg32<<<AGG32_B, 256, 0, stream>>>(bufH, als, ald, cursor, srclist, b3, bpart);
    pool_final<<<1, 256, 0, stream>>>(bpart, (float*)d_out);
}

// Round 9
// 452.209 us; speedup vs baseline: 1.8924x; 1.1317x over previous
//
#include <hip/hip_runtime.h>

// GAT (3-layer) on MI355X.
// R8: R7's pool_final was a single-block latency trap (93us, 0.03% hbm,
// 0.01% VALU -- 390 dependent L2-latency iterations on one CU). agg32 now
// atomicAdds its per-block 32-channel partial directly into d_out (zeroed
// via memset); pool_final and bpart eliminated.

typedef unsigned short bfu;
typedef unsigned char u8;
typedef __attribute__((ext_vector_type(8))) short bf16x8;
typedef __attribute__((ext_vector_type(4))) float f32x4;
typedef __attribute__((ext_vector_type(2))) float f32x2;

constexpr int N_NODES = 100000;
constexpr int E_IN    = 1600000;
constexpr int E_TOT   = E_IN + N_NODES;   // + self loops
constexpr float NEG   = 0.2f;
constexpr int P_XCD   = 8;
constexpr int PSZ     = N_NODES / P_XCD;  // 12500
constexpr int CAP     = 64;               // bucket slots/node (Poisson(16)+1)
constexpr int AGG32_B = N_NODES / 32;     // 3125 blocks, exact

__device__ inline bfu f2bf(float f) {
    union { float f; unsigned i; } c; c.f = f;
    unsigned x = c.i;
    return (bfu)((x + 0x7fffu + ((x >> 16) & 1u)) >> 16);
}
__device__ inline u8 f2fp8(float f) {
    return (u8)(__builtin_amdgcn_cvt_pk_fp8_f32(f, f, 0, false) & 0xff);
}

// ---------------- bucket CSR fill (dst-partitioned, XCD affinity) ----------

__global__ void fill_csr_part(const int* __restrict__ ei, int* __restrict__ cursor,
                              int* __restrict__ srclist) {
    int p = blockIdx.x & 7;
    int b = blockIdx.x >> 3;
    int lo = p * PSZ, hi = lo + PSZ;
    int e0 = (b * 256 + threadIdx.x) * 4;
    if (e0 >= E_TOT) return;
    bool self = e0 >= E_IN;
    int4 d4;
    if (!self) d4 = *(const int4*)&ei[E_IN + e0];
    else { int bb = e0 - E_IN; d4 = make_int4(bb, bb + 1, bb + 2, bb + 3); }
    int dd[4] = {d4.x, d4.y, d4.z, d4.w};
    #pragma unroll
    for (int q = 0; q < 4; ++q) {
        int d = dd[q];
        if (d >= lo && d < hi) {
            int s = self ? (e0 - E_IN + q) : ei[e0 + q];
            int pos = atomicAdd(&cursor[d], 1);
            if (pos < CAP) srclist[d * CAP + pos] = s;
        }
    }
}

// ---------------- prep: W -> W^T bf16 ----------------

__global__ void transpose_w(const float* __restrict__ W1, const float* __restrict__ W2,
                            const float* __restrict__ W3,
                            bfu* __restrict__ Wt1, bfu* __restrict__ Wt2,
                            bfu* __restrict__ Wt3) {
    int idx = blockIdx.x * 256 + threadIdx.x;
    if (idx < 16384) {
        int k = idx >> 7, n = idx & 127;
        Wt1[n * 128 + k] = f2bf(W1[idx]);
    } else if (idx < 32768) {
        int r = idx - 16384;
        int k = r >> 7, n = r & 127;
        Wt2[n * 128 + k] = f2bf(W2[r]);
    } else if (idx < 32768 + 4096) {
        int r = idx - 32768;
        int k = r >> 5, n = r & 31;
        Wt3[n * 128 + k] = f2bf(W3[r]);
    }
}

// ---------------- MFMA GEMM + fused logits; fp8 h output --------------------
// C/D layout: row = quad*4+r, col = nt*16+m -> head = nt (HID=16), ch = m.

__device__ inline bf16x8 ldcvt_f32(const float* p) {
    float4 v0 = *(const float4*)p;
    float4 v1 = *(const float4*)(p + 4);
    bf16x8 a;
    a[0] = (short)f2bf(v0.x); a[1] = (short)f2bf(v0.y);
    a[2] = (short)f2bf(v0.z); a[3] = (short)f2bf(v0.w);
    a[4] = (short)f2bf(v1.x); a[5] = (short)f2bf(v1.y);
    a[6] = (short)f2bf(v1.z); a[7] = (short)f2bf(v1.w);
    return a;
}

template<int COUT, bool F32A, int H>
__global__ __launch_bounds__(256) void gemm_mfma(const void* __restrict__ Xg_,
                                                 const bfu* __restrict__ Wt,
                                                 const float* __restrict__ a_src,
                                                 const float* __restrict__ a_dst,
                                                 u8* __restrict__ Y,
                                                 float* __restrict__ als,
                                                 float* __restrict__ ald) {
    constexpr int NT = COUT / 16;
    int wid  = threadIdx.x >> 6;
    int lane = threadIdx.x & 63;
    int m = lane & 15, quad = lane >> 4;
    int rbase = (blockIdx.x * 4 + wid) * 16;
    if (rbase >= N_NODES) return;
    int rA = rbase + m; if (rA >= N_NODES) rA = N_NODES - 1;

    bf16x8 a0, a1, a2, a3;
    if constexpr (F32A) {
        const float* Ap = (const float*)Xg_ + (size_t)rA * 128 + quad * 8;
        a0 = ldcvt_f32(Ap);
        a1 = ldcvt_f32(Ap + 32);
        a2 = ldcvt_f32(Ap + 64);
        a3 = ldcvt_f32(Ap + 96);
    } else {
        const bfu* Ap = (const bfu*)Xg_ + (size_t)rA * 128 + quad * 8;
        a0 = *(const bf16x8*)(Ap);
        a1 = *(const bf16x8*)(Ap + 32);
        a2 = *(const bf16x8*)(Ap + 64);
        a3 = *(const bf16x8*)(Ap + 96);
    }

    const bfu* Bp = Wt + (size_t)m * 128 + quad * 8;
    f32x4 acc[NT];
    #pragma unroll
    for (int nt = 0; nt < NT; nt++) {
        const bfu* Bn = Bp + nt * 16 * 128;
        f32x4 c = {0.f, 0.f, 0.f, 0.f};
        c = __builtin_amdgcn_mfma_f32_16x16x32_bf16(a0, *(const bf16x8*)(Bn),      c, 0, 0, 0);
        c = __builtin_amdgcn_mfma_f32_16x16x32_bf16(a1, *(const bf16x8*)(Bn + 32), c, 0, 0, 0);
        c = __builtin_amdgcn_mfma_f32_16x16x32_bf16(a2, *(const bf16x8*)(Bn + 64), c, 0, 0, 0);
        c = __builtin_amdgcn_mfma_f32_16x16x32_bf16(a3, *(const bf16x8*)(Bn + 96), c, 0, 0, 0);
        acc[nt] = c;
    }

    // fp8 store
    #pragma unroll
    for (int nt = 0; nt < NT; nt++) {
        #pragma unroll
        for (int r = 0; r < 4; r++) {
            int row = rbase + quad * 4 + r;
            if (row < N_NODES)
                Y[(size_t)row * COUT + nt * 16 + m] = f2fp8(acc[nt][r]);
        }
    }

    // fused logits
    if constexpr (H == 8) {
        #pragma unroll
        for (int nt = 0; nt < NT; nt++) {
            float as_ = a_src[nt * 16 + m];
            float ad_ = a_dst[nt * 16 + m];
            #pragma unroll
            for (int r = 0; r < 4; r++) {
                float vs = acc[nt][r] * as_;
                float vd = acc[nt][r] * ad_;
                #pragma unroll
                for (int mask = 1; mask < 16; mask <<= 1) {
                    vs += __shfl_xor(vs, mask);
                    vd += __shfl_xor(vd, mask);
                }
                int row = rbase + quad * 4 + r;
                if (m == 0 && row < N_NODES) {
                    als[row * 8 + nt] = vs;
                    ald[row * 8 + nt] = vd;
                }
            }
        }
    } else {  // H == 1, HID == 32, NT == 2
        float as0 = a_src[m], as1 = a_src[16 + m];
        float ad0 = a_dst[m], ad1 = a_dst[16 + m];
        #pragma unroll
        for (int r = 0; r < 4; r++) {
            float vs = acc[0][r] * as0 + acc[1][r] * as1;
            float vd = acc[0][r] * ad0 + acc[1][r] * ad1;
            #pragma unroll
            for (int mask = 1; mask < 16; mask <<= 1) {
                vs += __shfl_xor(vs, mask);
                vd += __shfl_xor(vd, mask);
            }
            int row = rbase + quad * 4 + r;
            if (m == 0 && row < N_NODES) {
                als[row] = vs;
                ald[row] = vd;
            }
        }
    }
}

// ---------------- aggregation (fp8 gather, bucket list, unroll x4) ----------
// agg128: 4 dst per wave; 16 lanes per dst; lane owns 8 channels (8B fp8 load).

__global__ __launch_bounds__(256) void agg128(const u8* __restrict__ Hb,
        const float* __restrict__ als, const float* __restrict__ ald,
        const int* __restrict__ deg, const int* __restrict__ srclist,
        const float* __restrict__ bias, bfu* __restrict__ out) {
    int wave = (blockIdx.x * 256 + threadIdx.x) >> 6;
    int lane = threadIdx.x & 63;
    int sub  = lane >> 4;
    int li   = lane & 15;
    int d    = wave * 4 + sub;
    if (d >= N_NODES) return;
    int c0 = li * 8;
    int h  = li >> 1;
    float ad = ald[d * 8 + h];
    const int* sl = srclist + d * CAP;
    int n = deg[d];
    float a0=0.f,a1=0.f,a2=0.f,a3=0.f,a4=0.f,a5=0.f,a6=0.f,a7=0.f,den=0.f;
    int j = 0;
    for (; j + 4 <= n; j += 4) {
        int s0 = sl[j], s1 = sl[j+1], s2 = sl[j+2], s3 = sl[j+3];
        uint2 u0 = *(const uint2*)(Hb + (size_t)s0 * 128 + c0);
        uint2 u1 = *(const uint2*)(Hb + (size_t)s1 * 128 + c0);
        uint2 u2 = *(const uint2*)(Hb + (size_t)s2 * 128 + c0);
        uint2 u3 = *(const uint2*)(Hb + (size_t)s3 * 128 + c0);
        float x0 = als[s0*8+h], x1 = als[s1*8+h], x2 = als[s2*8+h], x3 = als[s3*8+h];
        float l0 = x0 + ad; l0 = fmaxf(l0, NEG*l0); float w0 = __expf(l0);
        float l1 = x1 + ad; l1 = fmaxf(l1, NEG*l1); float w1 = __expf(l1);
        float l2 = x2 + ad; l2 = fmaxf(l2, NEG*l2); float w2 = __expf(l2);
        float l3 = x3 + ad; l3 = fmaxf(l3, NEG*l3); float w3 = __expf(l3);
        den += (w0 + w1) + (w2 + w3);
        {
            f32x2 p0 = __builtin_amdgcn_cvt_pk_f32_fp8((int)u0.x, false);
            f32x2 p1 = __builtin_amdgcn_cvt_pk_f32_fp8((int)u0.x, true);
            f32x2 p2 = __builtin_amdgcn_cvt_pk_f32_fp8((int)u0.y, false);
            f32x2 p3 = __builtin_amdgcn_cvt_pk_f32_fp8((int)u0.y, true);
            a0=fmaf(w0,p0[0],a0); a1=fmaf(w0,p0[1],a1); a2=fmaf(w0,p1[0],a2); a3=fmaf(w0,p1[1],a3);
            a4=fmaf(w0,p2[0],a4); a5=fmaf(w0,p2[1],a5); a6=fmaf(w0,p3[0],a6); a7=fmaf(w0,p3[1],a7);
        }
        {
            f32x2 p0 = __builtin_amdgcn_cvt_pk_f32_fp8((int)u1.x, false);
            f32x2 p1 = __builtin_amdgcn_cvt_pk_f32_fp8((int)u1.x, true);
            f32x2 p2 = __builtin_amdgcn_cvt_pk_f32_fp8((int)u1.y, false);
            f32x2 p3 = __builtin_amdgcn_cvt_pk_f32_fp8((int)u1.y, true);
            a0=fmaf(w1,p0[0],a0); a1=fmaf(w1,p0[1],a1); a2=fmaf(w1,p1[0],a2); a3=fmaf(w1,p1[1],a3);
            a4=fmaf(w1,p2[0],a4); a5=fmaf(w1,p2[1],a5); a6=fmaf(w1,p3[0],a6); a7=fmaf(w1,p3[1],a7);
        }
        {
            f32x2 p0 = __builtin_amdgcn_cvt_pk_f32_fp8((int)u2.x, false);
            f32x2 p1 = __builtin_amdgcn_cvt_pk_f32_fp8((int)u2.x, true);
            f32x2 p2 = __builtin_amdgcn_cvt_pk_f32_fp8((int)u2.y, false);
            f32x2 p3 = __builtin_amdgcn_cvt_pk_f32_fp8((int)u2.y, true);
            a0=fmaf(w2,p0[0],a0); a1=fmaf(w2,p0[1],a1); a2=fmaf(w2,p1[0],a2); a3=fmaf(w2,p1[1],a3);
            a4=fmaf(w2,p2[0],a4); a5=fmaf(w2,p2[1],a5); a6=fmaf(w2,p3[0],a6); a7=fmaf(w2,p3[1],a7);
        }
        {
            f32x2 p0 = __builtin_amdgcn_cvt_pk_f32_fp8((int)u3.x, false);
            f32x2 p1 = __builtin_amdgcn_cvt_pk_f32_fp8((int)u3.x, true);
            f32x2 p2 = __builtin_amdgcn_cvt_pk_f32_fp8((int)u3.y, false);
            f32x2 p3 = __builtin_amdgcn_cvt_pk_f32_fp8((int)u3.y, true);
            a0=fmaf(w3,p0[0],a0); a1=fmaf(w3,p0[1],a1); a2=fmaf(w3,p1[0],a2); a3=fmaf(w3,p1[1],a3);
            a4=fmaf(w3,p2[0],a4); a5=fmaf(w3,p2[1],a5); a6=fmaf(w3,p3[0],a6); a7=fmaf(w3,p3[1],a7);
        }
    }
    for (; j < n; ++j) {
        int s0 = sl[j];
        uint2 u0 = *(const uint2*)(Hb + (size_t)s0 * 128 + c0);
        float x0 = als[s0*8+h];
        float l0 = x0 + ad; l0 = fmaxf(l0, NEG*l0); float w0 = __expf(l0);
        den += w0;
        f32x2 p0 = __builtin_amdgcn_cvt_pk_f32_fp8((int)u0.x, false);
        f32x2 p1 = __builtin_amdgcn_cvt_pk_f32_fp8((int)u0.x, true);
        f32x2 p2 = __builtin_amdgcn_cvt_pk_f32_fp8((int)u0.y, false);
        f32x2 p3 = __builtin_amdgcn_cvt_pk_f32_fp8((int)u0.y, true);
        a0=fmaf(w0,p0[0],a0); a1=fmaf(w0,p0[1],a1); a2=fmaf(w0,p1[0],a2); a3=fmaf(w0,p1[1],a3);
        a4=fmaf(w0,p2[0],a4); a5=fmaf(w0,p2[1],a5); a6=fmaf(w0,p3[0],a6); a7=fmaf(w0,p3[1],a7);
    }
    float r = 1.f / den;
    float4 b0 = *(const float4*)&bias[c0];
    float4 b1 = *(const float4*)&bias[c0 + 4];
    float o0 = fmaxf(fmaf(a0, r, b0.x), 0.f);
    float o1 = fmaxf(fmaf(a1, r, b0.y), 0.f);
    float o2 = fmaxf(fmaf(a2, r, b0.z), 0.f);
    float o3 = fmaxf(fmaf(a3, r, b0.w), 0.f);
    float o4 = fmaxf(fmaf(a4, r, b1.x), 0.f);
    float o5 = fmaxf(fmaf(a5, r, b1.y), 0.f);
    float o6 = fmaxf(fmaf(a6, r, b1.z), 0.f);
    float o7 = fmaxf(fmaf(a7, r, b1.w), 0.f);
    uint4 st;
    st.x = (unsigned)f2bf(o0) | ((unsigned)f2bf(o1) << 16);
    st.y = (unsigned)f2bf(o2) | ((unsigned)f2bf(o3) << 16);
    st.z = (unsigned)f2bf(o4) | ((unsigned)f2bf(o5) << 16);
    st.w = (unsigned)f2bf(o6) | ((unsigned)f2bf(o7) << 16);
    *(uint4*)&out[(size_t)d * 128 + c0] = st;
}

// agg32 + fused mean pool: 8 dst/wave, 8 lanes/dst, lane owns 4 ch (4B fp8).
// Per-block 32-channel partial -> atomicAdd into d_out.
__global__ __launch_bounds__(256) void agg32(const u8* __restrict__ Hb,
        const float* __restrict__ als, const float* __restrict__ ald,
        const int* __restrict__ deg, const int* __restrict__ srclist,
        const float* __restrict__ bias, float* __restrict__ outp) {
    __shared__ float lds[4][32];
    int t    = threadIdx.x;
    int wid  = t >> 6;
    int lane = t & 63;
    int sub  = lane >> 3;
    int li   = lane & 7;
    int d    = blockIdx.x * 32 + wid * 8 + sub;   // exact: N_NODES % 32 == 0
    int c0 = li * 4;
    float adv = ald[d];
    const int* sl = srclist + d * CAP;
    int n = deg[d];
    float a0=0.f,a1=0.f,a2=0.f,a3=0.f,den=0.f;
    int j = 0;
    for (; j + 4 <= n; j += 4) {
        int s0 = sl[j], s1 = sl[j+1], s2 = sl[j+2], s3 = sl[j+3];
        unsigned u0 = *(const unsigned*)(Hb + (size_t)s0 * 32 + c0);
        unsigned u1 = *(const unsigned*)(Hb + (size_t)s1 * 32 + c0);
        unsigned u2 = *(const unsigned*)(Hb + (size_t)s2 * 32 + c0);
        unsigned u3 = *(const unsigned*)(Hb + (size_t)s3 * 32 + c0);
        float x0 = als[s0], x1 = als[s1], x2 = als[s2], x3 = als[s3];
        float l0 = x0 + adv; l0 = fmaxf(l0, NEG*l0); float w0 = __expf(l0);
        float l1 = x1 + adv; l1 = fmaxf(l1, NEG*l1); float w1 = __expf(l1);
        float l2 = x2 + adv; l2 = fmaxf(l2, NEG*l2); float w2 = __expf(l2);
        float l3 = x3 + adv; l3 = fmaxf(l3, NEG*l3); float w3 = __expf(l3);
        den += (w0 + w1) + (w2 + w3);
        f32x2 p;
        p = __builtin_amdgcn_cvt_pk_f32_fp8((int)u0, false); a0=fmaf(w0,p[0],a0); a1=fmaf(w0,p[1],a1);
        p = __builtin_amdgcn_cvt_pk_f32_fp8((int)u0, true);  a2=fmaf(w0,p[0],a2); a3=fmaf(w0,p[1],a3);
        p = __builtin_amdgcn_cvt_pk_f32_fp8((int)u1, false); a0=fmaf(w1,p[0],a0); a1=fmaf(w1,p[1],a1);
        p = __builtin_amdgcn_cvt_pk_f32_fp8((int)u1, true);  a2=fmaf(w1,p[0],a2); a3=fmaf(w1,p[1],a3);
        p = __builtin_amdgcn_cvt_pk_f32_fp8((int)u2, false); a0=fmaf(w2,p[0],a0); a1=fmaf(w2,p[1],a1);
        p = __builtin_amdgcn_cvt_pk_f32_fp8((int)u2, true);  a2=fmaf(w2,p[0],a2); a3=fmaf(w2,p[1],a3);
        p = __builtin_amdgcn_cvt_pk_f32_fp8((int)u3, false); a0=fmaf(w3,p[0],a0); a1=fmaf(w3,p[1],a1);
        p = __builtin_amdgcn_cvt_pk_f32_fp8((int)u3, true);  a2=fmaf(w3,p[0],a2); a3=fmaf(w3,p[1],a3);
    }
    for (; j < n; ++j) {
        int s0 = sl[j];
        unsigned u0 = *(const unsigned*)(Hb + (size_t)s0 * 32 + c0);
        float x0 = als[s0];
        float l0 = x0 + adv; l0 = fmaxf(l0, NEG*l0); float w0 = __expf(l0);
        den += w0;
        f32x2 p;
        p = __builtin_amdgcn_cvt_pk_f32_fp8((int)u0, false); a0=fmaf(w0,p[0],a0); a1=fmaf(w0,p[1],a1);
        p = __builtin_amdgcn_cvt_pk_f32_fp8((int)u0, true);  a2=fmaf(w0,p[0],a2); a3=fmaf(w0,p[1],a3);
    }
    float r = 1.f / den;
    float4 bv = *(const float4*)&bias[c0];
    float o0 = fmaf(a0, r, bv.x), o1 = fmaf(a1, r, bv.y);
    float o2 = fmaf(a2, r, bv.z), o3 = fmaf(a3, r, bv.w);
    // reduce over the 8 dst subs within the wave
    #pragma unroll
    for (int mask = 8; mask < 64; mask <<= 1) {
        o0 += __shfl_xor(o0, mask);
        o1 += __shfl_xor(o1, mask);
        o2 += __shfl_xor(o2, mask);
        o3 += __shfl_xor(o3, mask);
    }
    if (sub == 0) {
        lds[wid][c0]     = o0;
        lds[wid][c0 + 1] = o1;
        lds[wid][c0 + 2] = o2;
        lds[wid][c0 + 3] = o3;
    }
    __syncthreads();
    if (t < 32)
        atomicAdd(&outp[t],
            (lds[0][t] + lds[1][t] + lds[2][t] + lds[3][t]) * (1.0f / N_NODES));
}

// ---------------- launch ----------------

extern "C" void kernel_launch(void* const* d_in, const int* in_sizes, int n_in,
                              void* d_out, int out_size, void* d_ws, size_t ws_size,
                              hipStream_t stream) {
    (void)in_sizes; (void)n_in; (void)out_size; (void)ws_size;
    const float* x   = (const float*)d_in[0];
    const int*   ei  = (const int*)d_in[1];
    const float* W1  = (const float*)d_in[2];
    const float* as1 = (const float*)d_in[3];
    const float* ad1 = (const float*)d_in[4];
    const float* b1  = (const float*)d_in[5];
    const float* W2  = (const float*)d_in[6];
    const float* as2 = (const float*)d_in[7];
    const float* ad2 = (const float*)d_in[8];
    const float* b2  = (const float*)d_in[9];
    const float* W3  = (const float*)d_in[10];
    const float* as3 = (const float*)d_in[11];
    const float* ad3 = (const float*)d_in[12];
    const float* b3  = (const float*)d_in[13];

    char* ws = (char*)d_ws;
    size_t off = 0;
    auto carve = [&](size_t bytes) { void* p = ws + off; off += (bytes + 255) & ~size_t(255); return p; };
    u8*    bufH    = (u8*)carve(size_t(N_NODES) * 128);        // h (fp8 e4m3)
    bfu*   bufF    = (bfu*)carve(size_t(N_NODES) * 128 * 2);   // agg out (bf16)
    float* als     = (float*)carve(size_t(N_NODES) * 8 * 4);
    float* ald     = (float*)carve(size_t(N_NODES) * 8 * 4);
    int*   cursor  = (int*)carve(size_t(N_NODES) * 4);
    bfu*   Wt1     = (bfu*)carve(128 * 128 * 2);
    bfu*   Wt2     = (bfu*)carve(128 * 128 * 2);
    bfu*   Wt3     = (bfu*)carve(32 * 128 * 2);
    int*   srclist = (int*)carve(size_t(N_NODES) * CAP * 4);

    const int EDGE_B4 = (E_TOT / 4 + 255) / 256;   // 1661
    const int GEMM_B  = (N_NODES + 63) / 64;

    hipMemsetAsync(cursor, 0, size_t(N_NODES) * 4, stream);
    hipMemsetAsync(d_out, 0, 32 * 4, stream);

    transpose_w<<<(36864 + 255) / 256, 256, 0, stream>>>(W1, W2, W3, Wt1, Wt2, Wt3);
    fill_csr_part<<<EDGE_B4 * P_XCD, 256, 0, stream>>>(ei, cursor, srclist);

    // layer 1 (fp32 A, cvt in register)
    gemm_mfma<128, true, 8><<<GEMM_B, 256, 0, stream>>>(x, Wt1, as1, ad1, bufH, als, ald);
    agg128<<<(N_NODES + 15) / 16, 256, 0, stream>>>(bufH, als, ald, cursor, srclist, b1, bufF);

    // layer 2
    gemm_mfma<128, false, 8><<<GEMM_B, 256, 0, stream>>>(bufF, Wt2, as2, ad2, bufH, als, ald);
    agg128<<<(N_NODES + 15) / 16, 256, 0, stream>>>(bufH, als, ald, cursor, srclist, b2, bufF);

    // layer 3
    gemm_mfma<32, false, 1><<<GEMM_B, 256, 0, stream>>>(bufF, Wt3, as3, ad3, bufH, als, ald);
    agg32<<<AGG32_B, 256, 0, stream>>>(bufH, als, ald, cursor, srclist, b3, (float*)d_out);
}

// Round 10
// 451.352 us; speedup vs baseline: 1.8960x; 1.0019x over previous
//
#include <hip/hip_runtime.h>

// GAT (3-layer) on MI355X.
// R9: (a) fill's edge-stream loads are non-temporal (nt flag) -- R8 showed
//     WRITE_SIZE 86.5MB vs ~10MB useful: streaming ei reads thrash the dirty
//     3.2MB srclist window out of the XCD L2 (3-4 evictions/line + RMW).
//     (b) fill fused into gemm1's grid (independent work, both pre-agg128):
//     blocks < GEMM_B do GEMM+logits, rest do fill -> serial 25+45us -> max.

typedef unsigned short bfu;
typedef unsigned char u8;
typedef __attribute__((ext_vector_type(8))) short bf16x8;
typedef __attribute__((ext_vector_type(4))) float f32x4;
typedef __attribute__((ext_vector_type(2))) float f32x2;
typedef __attribute__((ext_vector_type(4))) int i32x4;

constexpr int N_NODES = 100000;
constexpr int E_IN    = 1600000;
constexpr int E_TOT   = E_IN + N_NODES;   // + self loops
constexpr float NEG   = 0.2f;
constexpr int P_XCD   = 8;
constexpr int PSZ     = N_NODES / P_XCD;  // 12500
constexpr int CAP     = 64;               // bucket slots/node (Poisson(16)+1)
constexpr int AGG32_B = N_NODES / 32;     // 3125 blocks, exact
constexpr int GEMM_B  = (N_NODES + 63) / 64;        // 1563
constexpr int EDGE_B4 = (E_TOT / 4 + 255) / 256;    // 1661
constexpr int FILL_B  = EDGE_B4 * P_XCD;            // 13288

__device__ inline bfu f2bf(float f) {
    union { float f; unsigned i; } c; c.f = f;
    unsigned x = c.i;
    return (bfu)((x + 0x7fffu + ((x >> 16) & 1u)) >> 16);
}
__device__ inline u8 f2fp8(float f) {
    return (u8)(__builtin_amdgcn_cvt_pk_fp8_f32(f, f, 0, false) & 0xff);
}

// ---------------- bucket CSR fill body (dst-partitioned, XCD affinity) ------
// nt loads: edge stream must not evict the dirty srclist window from L2.

__device__ inline void fill_body(int g, int tid, const int* __restrict__ ei,
                                 int* __restrict__ cursor, int* __restrict__ srclist) {
    int p = g & 7;
    int b = g >> 3;
    int lo = p * PSZ;
    int e0 = (b * 256 + tid) * 4;
    if (e0 >= E_TOT) return;
    bool self = e0 >= E_IN;
    i32x4 d4;
    if (!self) d4 = __builtin_nontemporal_load((const i32x4*)(ei + E_IN + e0));
    else { int bb = e0 - E_IN; d4 = (i32x4){bb, bb + 1, bb + 2, bb + 3}; }
    #pragma unroll
    for (int q = 0; q < 4; ++q) {
        int d = d4[q];
        if ((unsigned)(d - lo) < (unsigned)PSZ) {
            int s = self ? (e0 - E_IN + q) : __builtin_nontemporal_load(ei + e0 + q);
            int pos = atomicAdd(&cursor[d], 1);
            if (pos < CAP) srclist[d * CAP + pos] = s;
        }
    }
}

// ---------------- prep: W -> W^T bf16 ----------------

__global__ void transpose_w(const float* __restrict__ W1, const float* __restrict__ W2,
                            const float* __restrict__ W3,
                            bfu* __restrict__ Wt1, bfu* __restrict__ Wt2,
                            bfu* __restrict__ Wt3) {
    int idx = blockIdx.x * 256 + threadIdx.x;
    if (idx < 16384) {
        int k = idx >> 7, n = idx & 127;
        Wt1[n * 128 + k] = f2bf(W1[idx]);
    } else if (idx < 32768) {
        int r = idx - 16384;
        int k = r >> 7, n = r & 127;
        Wt2[n * 128 + k] = f2bf(W2[r]);
    } else if (idx < 32768 + 4096) {
        int r = idx - 32768;
        int k = r >> 5, n = r & 31;
        Wt3[n * 128 + k] = f2bf(W3[r]);
    }
}

// ---------------- MFMA GEMM + fused logits; fp8 h output --------------------
// C/D layout: row = quad*4+r, col = nt*16+m -> head = nt (HID=16), ch = m.

__device__ inline bf16x8 ldcvt_f32(const float* p) {
    float4 v0 = *(const float4*)p;
    float4 v1 = *(const float4*)(p + 4);
    bf16x8 a;
    a[0] = (short)f2bf(v0.x); a[1] = (short)f2bf(v0.y);
    a[2] = (short)f2bf(v0.z); a[3] = (short)f2bf(v0.w);
    a[4] = (short)f2bf(v1.x); a[5] = (short)f2bf(v1.y);
    a[6] = (short)f2bf(v1.z); a[7] = (short)f2bf(v1.w);
    return a;
}

template<int COUT, bool F32A, int H>
__device__ inline void gemm_body(int bidx, const void* __restrict__ Xg_,
                                 const bfu* __restrict__ Wt,
                                 const float* __restrict__ a_src,
                                 const float* __restrict__ a_dst,
                                 u8* __restrict__ Y,
                                 float* __restrict__ als,
                                 float* __restrict__ ald) {
    constexpr int NT = COUT / 16;
    int wid  = threadIdx.x >> 6;
    int lane = threadIdx.x & 63;
    int m = lane & 15, quad = lane >> 4;
    int rbase = (bidx * 4 + wid) * 16;
    if (rbase >= N_NODES) return;
    int rA = rbase + m; if (rA >= N_NODES) rA = N_NODES - 1;

    bf16x8 a0, a1, a2, a3;
    if constexpr (F32A) {
        const float* Ap = (const float*)Xg_ + (size_t)rA * 128 + quad * 8;
        a0 = ldcvt_f32(Ap);
        a1 = ldcvt_f32(Ap + 32);
        a2 = ldcvt_f32(Ap + 64);
        a3 = ldcvt_f32(Ap + 96);
    } else {
        const bfu* Ap = (const bfu*)Xg_ + (size_t)rA * 128 + quad * 8;
        a0 = *(const bf16x8*)(Ap);
        a1 = *(const bf16x8*)(Ap + 32);
        a2 = *(const bf16x8*)(Ap + 64);
        a3 = *(const bf16x8*)(Ap + 96);
    }

    const bfu* Bp = Wt + (size_t)m * 128 + quad * 8;
    f32x4 acc[NT];
    #pragma unroll
    for (int nt = 0; nt < NT; nt++) {
        const bfu* Bn = Bp + nt * 16 * 128;
        f32x4 c = {0.f, 0.f, 0.f, 0.f};
        c = __builtin_amdgcn_mfma_f32_16x16x32_bf16(a0, *(const bf16x8*)(Bn),      c, 0, 0, 0);
        c = __builtin_amdgcn_mfma_f32_16x16x32_bf16(a1, *(const bf16x8*)(Bn + 32), c, 0, 0, 0);
        c = __builtin_amdgcn_mfma_f32_16x16x32_bf16(a2, *(const bf16x8*)(Bn + 64), c, 0, 0, 0);
        c = __builtin_amdgcn_mfma_f32_16x16x32_bf16(a3, *(const bf16x8*)(Bn + 96), c, 0, 0, 0);
        acc[nt] = c;
    }

    #pragma unroll
    for (int nt = 0; nt < NT; nt++) {
        #pragma unroll
        for (int r = 0; r < 4; r++) {
            int row = rbase + quad * 4 + r;
            if (row < N_NODES)
                Y[(size_t)row * COUT + nt * 16 + m] = f2fp8(acc[nt][r]);
        }
    }

    if constexpr (H == 8) {
        #pragma unroll
        for (int nt = 0; nt < NT; nt++) {
            float as_ = a_src[nt * 16 + m];
            float ad_ = a_dst[nt * 16 + m];
            #pragma unroll
            for (int r = 0; r < 4; r++) {
                float vs = acc[nt][r] * as_;
                float vd = acc[nt][r] * ad_;
                #pragma unroll
                for (int mask = 1; mask < 16; mask <<= 1) {
                    vs += __shfl_xor(vs, mask);
                    vd += __shfl_xor(vd, mask);
                }
                int row = rbase + quad * 4 + r;
                if (m == 0 && row < N_NODES) {
                    als[row * 8 + nt] = vs;
                    ald[row * 8 + nt] = vd;
                }
            }
        }
    } else {  // H == 1, HID == 32, NT == 2
        float as0 = a_src[m], as1 = a_src[16 + m];
        float ad0 = a_dst[m], ad1 = a_dst[16 + m];
        #pragma unroll
        for (int r = 0; r < 4; r++) {
            float vs = acc[0][r] * as0 + acc[1][r] * as1;
            float vd = acc[0][r] * ad0 + acc[1][r] * ad1;
            #pragma unroll
            for (int mask = 1; mask < 16; mask <<= 1) {
                vs += __shfl_xor(vs, mask);
                vd += __shfl_xor(vd, mask);
            }
            int row = rbase + quad * 4 + r;
            if (m == 0 && row < N_NODES) {
                als[row] = vs;
                ald[row] = vd;
            }
        }
    }
}

// fused: blocks [0, GEMM_B) do layer-1 GEMM; [GEMM_B, GEMM_B+FILL_B) do fill.
__global__ __launch_bounds__(256) void gemm1_fill(const float* __restrict__ x,
        const bfu* __restrict__ Wt1, const float* __restrict__ as1,
        const float* __restrict__ ad1, u8* __restrict__ Y,
        float* __restrict__ als, float* __restrict__ ald,
        const int* __restrict__ ei, int* __restrict__ cursor,
        int* __restrict__ srclist) {
    if (blockIdx.x < GEMM_B)
        gemm_body<128, true, 8>(blockIdx.x, x, Wt1, as1, ad1, Y, als, ald);
    else
        fill_body(blockIdx.x - GEMM_B, threadIdx.x, ei, cursor, srclist);
}

template<int COUT, bool F32A, int H>
__global__ __launch_bounds__(256) void gemm_mfma(const void* __restrict__ Xg_,
                                                 const bfu* __restrict__ Wt,
                                                 const float* __restrict__ a_src,
                                                 const float* __restrict__ a_dst,
                                                 u8* __restrict__ Y,
                                                 float* __restrict__ als,
                                                 float* __restrict__ ald) {
    gemm_body<COUT, F32A, H>(blockIdx.x, Xg_, Wt, a_src, a_dst, Y, als, ald);
}

// ---------------- aggregation (fp8 gather, bucket list, unroll x4) ----------
// agg128: 4 dst per wave; 16 lanes per dst; lane owns 8 channels (8B fp8 load).

__global__ __launch_bounds__(256) void agg128(const u8* __restrict__ Hb,
        const float* __restrict__ als, const float* __restrict__ ald,
        const int* __restrict__ deg, const int* __restrict__ srclist,
        const float* __restrict__ bias, bfu* __restrict__ out) {
    int wave = (blockIdx.x * 256 + threadIdx.x) >> 6;
    int lane = threadIdx.x & 63;
    int sub  = lane >> 4;
    int li   = lane & 15;
    int d    = wave * 4 + sub;
    if (d >= N_NODES) return;
    int c0 = li * 8;
    int h  = li >> 1;
    float ad = ald[d * 8 + h];
    const int* sl = srclist + d * CAP;
    int n = deg[d];
    float a0=0.f,a1=0.f,a2=0.f,a3=0.f,a4=0.f,a5=0.f,a6=0.f,a7=0.f,den=0.f;
    int j = 0;
    for (; j + 4 <= n; j += 4) {
        int s0 = sl[j], s1 = sl[j+1], s2 = sl[j+2], s3 = sl[j+3];
        uint2 u0 = *(const uint2*)(Hb + (size_t)s0 * 128 + c0);
        uint2 u1 = *(const uint2*)(Hb + (size_t)s1 * 128 + c0);
        uint2 u2 = *(const uint2*)(Hb + (size_t)s2 * 128 + c0);
        uint2 u3 = *(const uint2*)(Hb + (size_t)s3 * 128 + c0);
        float x0 = als[s0*8+h], x1 = als[s1*8+h], x2 = als[s2*8+h], x3 = als[s3*8+h];
        float l0 = x0 + ad; l0 = fmaxf(l0, NEG*l0); float w0 = __expf(l0);
        float l1 = x1 + ad; l1 = fmaxf(l1, NEG*l1); float w1 = __expf(l1);
        float l2 = x2 + ad; l2 = fmaxf(l2, NEG*l2); float w2 = __expf(l2);
        float l3 = x3 + ad; l3 = fmaxf(l3, NEG*l3); float w3 = __expf(l3);
        den += (w0 + w1) + (w2 + w3);
        {
            f32x2 p0 = __builtin_amdgcn_cvt_pk_f32_fp8((int)u0.x, false);
            f32x2 p1 = __builtin_amdgcn_cvt_pk_f32_fp8((int)u0.x, true);
            f32x2 p2 = __builtin_amdgcn_cvt_pk_f32_fp8((int)u0.y, false);
            f32x2 p3 = __builtin_amdgcn_cvt_pk_f32_fp8((int)u0.y, true);
            a0=fmaf(w0,p0[0],a0); a1=fmaf(w0,p0[1],a1); a2=fmaf(w0,p1[0],a2); a3=fmaf(w0,p1[1],a3);
            a4=fmaf(w0,p2[0],a4); a5=fmaf(w0,p2[1],a5); a6=fmaf(w0,p3[0],a6); a7=fmaf(w0,p3[1],a7);
        }
        {
            f32x2 p0 = __builtin_amdgcn_cvt_pk_f32_fp8((int)u1.x, false);
            f32x2 p1 = __builtin_amdgcn_cvt_pk_f32_fp8((int)u1.x, true);
            f32x2 p2 = __builtin_amdgcn_cvt_pk_f32_fp8((int)u1.y, false);
            f32x2 p3 = __builtin_amdgcn_cvt_pk_f32_fp8((int)u1.y, true);
            a0=fmaf(w1,p0[0],a0); a1=fmaf(w1,p0[1],a1); a2=fmaf(w1,p1[0],a2); a3=fmaf(w1,p1[1],a3);
            a4=fmaf(w1,p2[0],a4); a5=fmaf(w1,p2[1],a5); a6=fmaf(w1,p3[0],a6); a7=fmaf(w1,p3[1],a7);
        }
        {
            f32x2 p0 = __builtin_amdgcn_cvt_pk_f32_fp8((int)u2.x, false);
            f32x2 p1 = __builtin_amdgcn_cvt_pk_f32_fp8((int)u2.x, true);
            f32x2 p2 = __builtin_amdgcn_cvt_pk_f32_fp8((int)u2.y, false);
            f32x2 p3 = __builtin_amdgcn_cvt_pk_f32_fp8((int)u2.y, true);
            a0=fmaf(w2,p0[0],a0); a1=fmaf(w2,p0[1],a1); a2=fmaf(w2,p1[0],a2); a3=fmaf(w2,p1[1],a3);
            a4=fmaf(w2,p2[0],a4); a5=fmaf(w2,p2[1],a5); a6=fmaf(w2,p3[0],a6); a7=fmaf(w2,p3[1],a7);
        }
        {
            f32x2 p0 = __builtin_amdgcn_cvt_pk_f32_fp8((int)u3.x, false);
            f32x2 p1 = __builtin_amdgcn_cvt_pk_f32_fp8((int)u3.x, true);
            f32x2 p2 = __builtin_amdgcn_cvt_pk_f32_fp8((int)u3.y, false);
            f32x2 p3 = __builtin_amdgcn_cvt_pk_f32_fp8((int)u3.y, true);
            a0=fmaf(w3,p0[0],a0); a1=fmaf(w3,p0[1],a1); a2=fmaf(w3,p1[0],a2); a3=fmaf(w3,p1[1],a3);
            a4=fmaf(w3,p2[0],a4); a5=fmaf(w3,p2[1],a5); a6=fmaf(w3,p3[0],a6); a7=fmaf(w3,p3[1],a7);
        }
    }
    for (; j < n; ++j) {
        int s0 = sl[j];
        uint2 u0 = *(const uint2*)(Hb + (size_t)s0 * 128 + c0);
        float x0 = als[s0*8+h];
        float l0 = x0 + ad; l0 = fmaxf(l0, NEG*l0); float w0 = __expf(l0);
        den += w0;
        f32x2 p0 = __builtin_amdgcn_cvt_pk_f32_fp8((int)u0.x, false);
        f32x2 p1 = __builtin_amdgcn_cvt_pk_f32_fp8((int)u0.x, true);
        f32x2 p2 = __builtin_amdgcn_cvt_pk_f32_fp8((int)u0.y, false);
        f32x2 p3 = __builtin_amdgcn_cvt_pk_f32_fp8((int)u0.y, true);
        a0=fmaf(w0,p0[0],a0); a1=fmaf(w0,p0[1],a1); a2=fmaf(w0,p1[0],a2); a3=fmaf(w0,p1[1],a3);
        a4=fmaf(w0,p2[0],a4); a5=fmaf(w0,p2[1],a5); a6=fmaf(w0,p3[0],a6); a7=fmaf(w0,p3[1],a7);
    }
    float r = 1.f / den;
    float4 b0 = *(const float4*)&bias[c0];
    float4 b1 = *(const float4*)&bias[c0 + 4];
    float o0 = fmaxf(fmaf(a0, r, b0.x), 0.f);
    float o1 = fmaxf(fmaf(a1, r, b0.y), 0.f);
    float o2 = fmaxf(fmaf(a2, r, b0.z), 0.f);
    float o3 = fmaxf(fmaf(a3, r, b0.w), 0.f);
    float o4 = fmaxf(fmaf(a4, r, b1.x), 0.f);
    float o5 = fmaxf(fmaf(a5, r, b1.y), 0.f);
    float o6 = fmaxf(fmaf(a6, r, b1.z), 0.f);
    float o7 = fmaxf(fmaf(a7, r, b1.w), 0.f);
    uint4 st;
    st.x = (unsigned)f2bf(o0) | ((unsigned)f2bf(o1) << 16);
    st.y = (unsigned)f2bf(o2) | ((unsigned)f2bf(o3) << 16);
    st.z = (unsigned)f2bf(o4) | ((unsigned)f2bf(o5) << 16);
    st.w = (unsigned)f2bf(o6) | ((unsigned)f2bf(o7) << 16);
    *(uint4*)&out[(size_t)d * 128 + c0] = st;
}

// agg32 + fused mean pool: 8 dst/wave, 8 lanes/dst, lane owns 4 ch (4B fp8).
__global__ __launch_bounds__(256) void agg32(const u8* __restrict__ Hb,
        const float* __restrict__ als, const float* __restrict__ ald,
        const int* __restrict__ deg, const int* __restrict__ srclist,
        const float* __restrict__ bias, float* __restrict__ outp) {
    __shared__ float lds[4][32];
    int t    = threadIdx.x;
    int wid  = t >> 6;
    int lane = t & 63;
    int sub  = lane >> 3;
    int li   = lane & 7;
    int d    = blockIdx.x * 32 + wid * 8 + sub;   // exact: N_NODES % 32 == 0
    int c0 = li * 4;
    float adv = ald[d];
    const int* sl = srclist + d * CAP;
    int n = deg[d];
    float a0=0.f,a1=0.f,a2=0.f,a3=0.f,den=0.f;
    int j = 0;
    for (; j + 4 <= n; j += 4) {
        int s0 = sl[j], s1 = sl[j+1], s2 = sl[j+2], s3 = sl[j+3];
        unsigned u0 = *(const unsigned*)(Hb + (size_t)s0 * 32 + c0);
        unsigned u1 = *(const unsigned*)(Hb + (size_t)s1 * 32 + c0);
        unsigned u2 = *(const unsigned*)(Hb + (size_t)s2 * 32 + c0);
        unsigned u3 = *(const unsigned*)(Hb + (size_t)s3 * 32 + c0);
        float x0 = als[s0], x1 = als[s1], x2 = als[s2], x3 = als[s3];
        float l0 = x0 + adv; l0 = fmaxf(l0, NEG*l0); float w0 = __expf(l0);
        float l1 = x1 + adv; l1 = fmaxf(l1, NEG*l1); float w1 = __expf(l1);
        float l2 = x2 + adv; l2 = fmaxf(l2, NEG*l2); float w2 = __expf(l2);
        float l3 = x3 + adv; l3 = fmaxf(l3, NEG*l3); float w3 = __expf(l3);
        den += (w0 + w1) + (w2 + w3);
        f32x2 p;
        p = __builtin_amdgcn_cvt_pk_f32_fp8((int)u0, false); a0=fmaf(w0,p[0],a0); a1=fmaf(w0,p[1],a1);
        p = __builtin_amdgcn_cvt_pk_f32_fp8((int)u0, true);  a2=fmaf(w0,p[0],a2); a3=fmaf(w0,p[1],a3);
        p = __builtin_amdgcn_cvt_pk_f32_fp8((int)u1, false); a0=fmaf(w1,p[0],a0); a1=fmaf(w1,p[1],a1);
        p = __builtin_amdgcn_cvt_pk_f32_fp8((int)u1, true);  a2=fmaf(w1,p[0],a2); a3=fmaf(w1,p[1],a3);
        p = __builtin_amdgcn_cvt_pk_f32_fp8((int)u2, false); a0=fmaf(w2,p[0],a0); a1=fmaf(w2,p[1],a1);
        p = __builtin_amdgcn_cvt_pk_f32_fp8((int)u2, true);  a2=fmaf(w2,p[0],a2); a3=fmaf(w2,p[1],a3);
        p = __builtin_amdgcn_cvt_pk_f32_fp8((int)u3, false); a0=fmaf(w3,p[0],a0); a1=fmaf(w3,p[1],a1);
        p = __builtin_amdgcn_cvt_pk_f32_fp8((int)u3, true);  a2=fmaf(w3,p[0],a2); a3=fmaf(w3,p[1],a3);
    }
    for (; j < n; ++j) {
        int s0 = sl[j];
        unsigned u0 = *(const unsigned*)(Hb + (size_t)s0 * 32 + c0);
        float x0 = als[s0];
        float l0 = x0 + adv; l0 = fmaxf(l0, NEG*l0); float w0 = __expf(l0);
        den += w0;
        f32x2 p;
        p = __builtin_amdgcn_cvt_pk_f32_fp8((int)u0, false); a0=fmaf(w0,p[0],a0); a1=fmaf(w0,p[1],a1);
        p = __builtin_amdgcn_cvt_pk_f32_fp8((int)u0, true);  a2=fmaf(w0,p[0],a2); a3=fmaf(w0,p[1],a3);
    }
    float r = 1.f / den;
    float4 bv = *(const float4*)&bias[c0];
    float o0 = fmaf(a0, r, bv.x), o1 = fmaf(a1, r, bv.y);
    float o2 = fmaf(a2, r, bv.z), o3 = fmaf(a3, r, bv.w);
    #pragma unroll
    for (int mask = 8; mask < 64; mask <<= 1) {
        o0 += __shfl_xor(o0, mask);
        o1 += __shfl_xor(o1, mask);
        o2 += __shfl_xor(o2, mask);
        o3 += __shfl_xor(o3, mask);
    }
    if (sub == 0) {
        lds[wid][c0]     = o0;
        lds[wid][c0 + 1] = o1;
        lds[wid][c0 + 2] = o2;
        lds[wid][c0 + 3] = o3;
    }
    __syncthreads();
    if (t < 32)
        atomicAdd(&outp[t],
            (lds[0][t] + lds[1][t] + lds[2][t] + lds[3][t]) * (1.0f / N_NODES));
}

// ---------------- launch ----------------

extern "C" void kernel_launch(void* const* d_in, const int* in_sizes, int n_in,
                              void* d_out, int out_size, void* d_ws, size_t ws_size,
                              hipStream_t stream) {
    (void)in_sizes; (void)n_in; (void)out_size; (void)ws_size;
    const float* x   = (const float*)d_in[0];
    const int*   ei  = (const int*)d_in[1];
    const float* W1  = (const float*)d_in[2];
    const float* as1 = (const float*)d_in[3];
    const float* ad1 = (const float*)d_in[4];
    const float* b1  = (const float*)d_in[5];
    const float* W2  = (const float*)d_in[6];
    const float* as2 = (const float*)d_in[7];
    const float* ad2 = (const float*)d_in[8];
    const float* b2  = (const float*)d_in[9];
    const float* W3  = (const float*)d_in[10];
    const float* as3 = (const float*)d_in[11];
    const float* ad3 = (const float*)d_in[12];
    const float* b3  = (const float*)d_in[13];

    char* ws = (char*)d_ws;
    size_t off = 0;
    auto carve = [&](size_t bytes) { void* p = ws + off; off += (bytes + 255) & ~size_t(255); return p; };
    u8*    bufH    = (u8*)carve(size_t(N_NODES) * 128);        // h (fp8 e4m3)
    bfu*   bufF    = (bfu*)carve(size_t(N_NODES) * 128 * 2);   // agg out (bf16)
    float* als     = (float*)carve(size_t(N_NODES) * 8 * 4);
    float* ald     = (float*)carve(size_t(N_NODES) * 8 * 4);
    int*   cursor  = (int*)carve(size_t(N_NODES) * 4);
    bfu*   Wt1     = (bfu*)carve(128 * 128 * 2);
    bfu*   Wt2     = (bfu*)carve(128 * 128 * 2);
    bfu*   Wt3     = (bfu*)carve(32 * 128 * 2);
    int*   srclist = (int*)carve(size_t(N_NODES) * CAP * 4);

    hipMemsetAsync(cursor, 0, size_t(N_NODES) * 4, stream);
    hipMemsetAsync(d_out, 0, 32 * 4, stream);

    transpose_w<<<(36864 + 255) / 256, 256, 0, stream>>>(W1, W2, W3, Wt1, Wt2, Wt3);

    // layer-1 GEMM (fp32 A) fused with CSR fill in one grid
    gemm1_fill<<<GEMM_B + FILL_B, 256, 0, stream>>>(x, Wt1, as1, ad1, bufH, als, ald,
                                                    ei, cursor, srclist);
    agg128<<<(N_NODES + 15) / 16, 256, 0, stream>>>(bufH, als, ald, cursor, srclist, b1, bufF);

    // layer 2
    gemm_mfma<128, false, 8><<<GEMM_B, 256, 0, stream>>>(bufF, Wt2, as2, ad2, bufH, als, ald);
    agg128<<<(N_NODES + 15) / 16, 256, 0, stream>>>(bufH, als, ald, cursor, srclist, b2, bufF);

    // layer 3
    gemm_mfma<32, false, 1><<<GEMM_B, 256, 0, stream>>>(bufF, Wt3, as3, ad3, bufH, als, ald);
    agg32<<<AGG32_B, 256, 0, stream>>>(bufH, als, ald, cursor, srclist, b3, (float*)d_out);
}